// Round 5
// baseline (474.205 us; speedup 1.0000x reference)
//
#include <hip/hip_runtime.h>

// ---------------------------------------------------------------------------
// RegionalCrossAttention on MI355X (gfx950).  fp32 in / fp32 out.
// B=2, n=8, L=4096, Lt=77, d=1024, ctx=768, H=16 heads x 64.
//
//   Q = x@Wq once per batch (x broadcast over n)  -> fp32, stored in d_out.
//   K -> Kp[bn][80][1024]   (bf16, t padded to 80 with zero rows)
//   V -> Vt[bn][1024][96]   (bf16, TRANSPOSED, t padded to 96 with zeros)
//   attn IN-PLACE on d_out (bijective 32x64 tiles), softmax without max-pass.
//   out = ACC@Wo + cover*bo + (1-cover)*null + x, IN-PLACE on d_out.
//
// Round 5: all heavy kernels use 4-wave (256-thread) workgroups — 1-wave
// blocks were capped by the per-CU workgroup-slot limit (Occupancy 21.6%).
// attn P-buffer stride 96 -> 104 (4-way -> 2-way LDS write conflicts).
// Workspace: 13.14 MB.
// ---------------------------------------------------------------------------

typedef __bf16 bf16;
typedef __bf16 bf16x8 __attribute__((ext_vector_type(8)));
typedef __bf16 bf16x4 __attribute__((ext_vector_type(4)));
typedef float  f32x4  __attribute__((ext_vector_type(4)));

#define MFMA16(a, b, c) __builtin_amdgcn_mfma_f32_16x16x32_bf16((a), (b), (c), 0, 0, 0)

// v_mfma_f32_16x16x32_bf16 layouts (HW-verified, learn_hip m89/m120):
//   A: lane holds A[m = lane&15][k = 8*(lane>>4) + j], j=0..7
//   B: lane holds B[k = 8*(lane>>4) + j][n = lane&15]
//   D: lane,reg r holds D[m = 4*(lane>>4) + r][n = lane&15]

__device__ inline bf16x8 cvt8(const float* p) {
  f32x4 a = *(const f32x4*)p;
  f32x4 b = *(const f32x4*)(p + 4);
  bf16x8 r;
  r[0] = (bf16)a[0]; r[1] = (bf16)a[1]; r[2] = (bf16)a[2]; r[3] = (bf16)a[3];
  r[4] = (bf16)b[0]; r[5] = (bf16)b[1]; r[6] = (bf16)b[2]; r[7] = (bf16)b[3];
  return r;
}

// ---------------------------------------------------------------------------
// Transpose + downcast: out_bf16[c][r] = (bf16)in_f32[r][c].  R,C mult of 32.
// ---------------------------------------------------------------------------
__global__ __launch_bounds__(256) void transpose_cvt_k(const float* __restrict__ in,
                                                       bf16* __restrict__ out,
                                                       int R, int C) {
  __shared__ bf16 tile[32][33];
  int tx = threadIdx.x & 31, ty = threadIdx.x >> 5;
  int bx = blockIdx.x, by = blockIdx.y;
  int c = bx * 32 + tx;
#pragma unroll
  for (int i = 0; i < 32; i += 8) {
    int r = by * 32 + ty + i;
    tile[ty + i][tx] = (bf16)in[(size_t)r * C + c];
  }
  __syncthreads();
#pragma unroll
  for (int i = 0; i < 32; i += 8) {
    out[(size_t)(bx * 32 + ty + i) * R + by * 32 + tx] = tile[tx][ty + i];
  }
}

// ---------------------------------------------------------------------------
// Q GEMM: C_f32[M,N] = A_f32[M,K] @ BT_bf16[N,K]^T.
// 4 waves/block; wave w -> 64x64 quadrant of a 128x128 tile.
// ---------------------------------------------------------------------------
__global__ __launch_bounds__(256) void gemm_q_kernel(const float* __restrict__ A,
                                                     const bf16* __restrict__ BT,
                                                     float* __restrict__ C,
                                                     int M, int N, int K) {
  const int tid = threadIdx.x;
  const int lane = tid & 63, wave = tid >> 6;
  const int l16 = lane & 15, quad = lane >> 4;
  const int m0 = blockIdx.y * 128 + (wave >> 1) * 64;
  const int n0 = blockIdx.x * 128 + (wave & 1) * 64;

  f32x4 acc[4][4];
#pragma unroll
  for (int i = 0; i < 4; i++)
#pragma unroll
    for (int j = 0; j < 4; j++)
#pragma unroll
      for (int r = 0; r < 4; r++) acc[i][j][r] = 0.f;

  for (int k0 = 0; k0 < K; k0 += 32) {
    bf16x8 a[4], b[4];
#pragma unroll
    for (int mi = 0; mi < 4; mi++)
      a[mi] = cvt8(A + (size_t)(m0 + mi * 16 + l16) * K + k0 + quad * 8);
#pragma unroll
    for (int ni = 0; ni < 4; ni++)
      b[ni] = *(const bf16x8*)(BT + (size_t)(n0 + ni * 16 + l16) * K + k0 + quad * 8);
#pragma unroll
    for (int mi = 0; mi < 4; mi++)
#pragma unroll
      for (int ni = 0; ni < 4; ni++) acc[mi][ni] = MFMA16(a[mi], b[ni], acc[mi][ni]);
  }

#pragma unroll
  for (int mi = 0; mi < 4; mi++)
#pragma unroll
    for (int r = 0; r < 4; r++) {
      int row = m0 + mi * 16 + quad * 4 + r;
#pragma unroll
      for (int ni = 0; ni < 4; ni++)
        C[(size_t)row * N + n0 + ni * 16 + l16] = acc[mi][ni][r];
    }
}

// ---------------------------------------------------------------------------
// K GEMM with padded store: Kp[bn][80][1024] bf16; t rows 77..79 zeroed.
// grid (8, 16bn), 4 waves: m0 = (w>>1)*64, n0 = bx*128 + (w&1)*64.
// ---------------------------------------------------------------------------
__global__ __launch_bounds__(256) void gemm_k_pad(const float* __restrict__ text,
                                                  const bf16* __restrict__ WkT,
                                                  bf16* __restrict__ Kp) {
  const int tid = threadIdx.x;
  const int lane = tid & 63, wave = tid >> 6;
  const int l16 = lane & 15, quad = lane >> 4;
  const int m0 = (wave >> 1) * 64;
  const int n0 = blockIdx.x * 128 + (wave & 1) * 64;
  const int bn = blockIdx.y;
  const float* A = text + (size_t)bn * 77 * 768;
  bf16* dst = Kp + (size_t)bn * 80 * 1024;

  f32x4 acc[4][4];
#pragma unroll
  for (int i = 0; i < 4; i++)
#pragma unroll
    for (int j = 0; j < 4; j++)
#pragma unroll
      for (int r = 0; r < 4; r++) acc[i][j][r] = 0.f;

  for (int k0 = 0; k0 < 768; k0 += 32) {
    bf16x8 a[4], b[4];
#pragma unroll
    for (int mi = 0; mi < 4; mi++) {
      int row = m0 + mi * 16 + l16;
      if (row >= 77) row = 76;  // safe read; store guarded
      a[mi] = cvt8(A + (size_t)row * 768 + k0 + quad * 8);
    }
#pragma unroll
    for (int ni = 0; ni < 4; ni++)
      b[ni] = *(const bf16x8*)(WkT + (size_t)(n0 + ni * 16 + l16) * 768 + k0 + quad * 8);
#pragma unroll
    for (int mi = 0; mi < 4; mi++)
#pragma unroll
      for (int ni = 0; ni < 4; ni++) acc[mi][ni] = MFMA16(a[mi], b[ni], acc[mi][ni]);
  }

#pragma unroll
  for (int mi = 0; mi < 4; mi++)
#pragma unroll
    for (int r = 0; r < 4; r++) {
      int t = m0 + mi * 16 + quad * 4 + r;
      if (t < 77) {
#pragma unroll
        for (int ni = 0; ni < 4; ni++)
          dst[(size_t)t * 1024 + n0 + ni * 16 + l16] = (bf16)acc[mi][ni][r];
      } else if (t < 80) {
#pragma unroll
        for (int ni = 0; ni < 4; ni++)
          dst[(size_t)t * 1024 + n0 + ni * 16 + l16] = (bf16)0.f;
      }
    }
}

// ---------------------------------------------------------------------------
// V GEMM with TRANSPOSED padded store: Vt[bn][1024][96] bf16 (t contiguous),
// t in [77,96) zeroed. Same grid as gemm_k_pad.
// ---------------------------------------------------------------------------
__global__ __launch_bounds__(256) void gemm_v_t(const float* __restrict__ text,
                                                const bf16* __restrict__ WvT,
                                                bf16* __restrict__ Vt) {
  const int tid = threadIdx.x;
  const int lane = tid & 63, wave = tid >> 6;
  const int l16 = lane & 15, quad = lane >> 4;
  const int m0 = (wave >> 1) * 64;
  const int n0 = blockIdx.x * 128 + (wave & 1) * 64;
  const int bn = blockIdx.y;
  const float* A = text + (size_t)bn * 77 * 768;
  bf16* dst = Vt + (size_t)bn * 1024 * 96;

  f32x4 acc[4][4];
#pragma unroll
  for (int i = 0; i < 4; i++)
#pragma unroll
    for (int j = 0; j < 4; j++)
#pragma unroll
      for (int r = 0; r < 4; r++) acc[i][j][r] = 0.f;

  for (int k0 = 0; k0 < 768; k0 += 32) {
    bf16x8 a[4], b[4];
#pragma unroll
    for (int mi = 0; mi < 4; mi++) {
      int row = m0 + mi * 16 + l16;
      if (row >= 77) row = 76;
      a[mi] = cvt8(A + (size_t)row * 768 + k0 + quad * 8);
    }
#pragma unroll
    for (int ni = 0; ni < 4; ni++)
      b[ni] = *(const bf16x8*)(WvT + (size_t)(n0 + ni * 16 + l16) * 768 + k0 + quad * 8);
#pragma unroll
    for (int mi = 0; mi < 4; mi++)
#pragma unroll
      for (int ni = 0; ni < 4; ni++) acc[mi][ni] = MFMA16(a[mi], b[ni], acc[mi][ni]);
  }

#pragma unroll
  for (int mi = 0; mi < 4; mi++) {
    int t0 = m0 + mi * 16 + quad * 4;
#pragma unroll
    for (int ni = 0; ni < 4; ni++) {
      int col = n0 + ni * 16 + l16;
      bf16* cbase = dst + (size_t)col * 96;
      if (t0 + 3 < 77) {
        bf16x4 w;
        w[0] = (bf16)acc[mi][ni][0]; w[1] = (bf16)acc[mi][ni][1];
        w[2] = (bf16)acc[mi][ni][2]; w[3] = (bf16)acc[mi][ni][3];
        *(bf16x4*)(cbase + t0) = w;
      } else {
#pragma unroll
        for (int r = 0; r < 4; r++) {
          int t = t0 + r;
          if (t < 77)      cbase[t] = (bf16)acc[mi][ni][r];
          else if (t < 96) cbase[t] = (bf16)0.f;
        }
      }
    }
  }
}

// ---------------------------------------------------------------------------
// cover[b,l] = sum_n (mask[b,n,l] > 0.5)
// ---------------------------------------------------------------------------
__global__ __launch_bounds__(256) void cover_kernel(const float* __restrict__ mask,
                                                    float* __restrict__ cover) {
  int tid = blockIdx.x * 256 + threadIdx.x;
  int b = tid >> 12, l = tid & 4095;
  float c = 0.f;
#pragma unroll
  for (int n = 0; n < 8; n++)
    c += (mask[(size_t)(b * 8 + n) * 4096 + l] > 0.5f) ? 1.f : 0.f;
  cover[tid] = c;
}

// ---------------------------------------------------------------------------
// Attention, IN-PLACE on fp32 QO. 4 waves/block, wave w -> q-rows
// [qg*128 + w*32, +32) of head h. Same-head waves share K/V via L1.
// Per-wave private P buffer, stride 104 (2-way bank conflicts = free).
// ---------------------------------------------------------------------------
__global__ __launch_bounds__(256) void attn_kernel(float* QO,                    // (B*4096,1024)
                                                   const bf16* __restrict__ Kp,  // (16,80,1024)
                                                   const bf16* __restrict__ Vt,  // (16,1024,96)
                                                   const float* __restrict__ mask) { // (2,8,4096)
  __shared__ __align__(16) bf16 p_lds[4][32 * 104];  // 26,624 B
  const int tid = threadIdx.x;
  const int lane = tid & 63, wave = tid >> 6;
  const int l16 = lane & 15, quad = lane >> 4;
  const int bid = blockIdx.x;            // 1024 blocks
  const int qg = bid & 31;               // 32 groups of 128 q-rows
  const int h = (bid >> 5) & 15;
  const int b = bid >> 9;
  const int qrow0 = qg * 128 + wave * 32;
  bf16* pl = &p_lds[wave][0];

  // zero PV padding columns 80..95 once (softmax writes only cols 0..79)
  for (int i = lane; i < 32 * 16; i += 64) {
    int r = i >> 4, c = 80 + (i & 15);
    pl[r * 104 + c] = (bf16)0.f;
  }

  bf16x8 qf[2][2];
#pragma unroll
  for (int mi = 0; mi < 2; mi++)
#pragma unroll
    for (int ks = 0; ks < 2; ks++)
      qf[mi][ks] = cvt8(QO + (size_t)(b * 4096 + qrow0 + mi * 16 + l16) * 1024 +
                        h * 64 + ks * 32 + quad * 8);

  f32x4 oacc[2][4];
#pragma unroll
  for (int mi = 0; mi < 2; mi++)
#pragma unroll
    for (int nt = 0; nt < 4; nt++)
#pragma unroll
      for (int r = 0; r < 4; r++) oacc[mi][nt][r] = 0.f;

  for (int n = 0; n < 8; n++) {
    const int bn = b * 8 + n;
    const bf16* Kb = Kp + (size_t)bn * 80 * 1024 + h * 64;
    const bf16* Vb = Vt + (size_t)bn * 1024 * 96 + (size_t)h * 64 * 96;

    // --- S = Q K^T  (t = tt*16+l16 < 80, always in-bounds) ---
    f32x4 s[2][5];
#pragma unroll
    for (int mi = 0; mi < 2; mi++)
#pragma unroll
      for (int tt = 0; tt < 5; tt++)
#pragma unroll
        for (int r = 0; r < 4; r++) s[mi][tt][r] = 0.f;

#pragma unroll
    for (int tt = 0; tt < 5; tt++) {
      int t = tt * 16 + l16;
      bf16x8 kf0 = *(const bf16x8*)(Kb + (size_t)t * 1024 + quad * 8);
      bf16x8 kf1 = *(const bf16x8*)(Kb + (size_t)t * 1024 + 32 + quad * 8);
#pragma unroll
      for (int mi = 0; mi < 2; mi++) {
        s[mi][tt] = MFMA16(qf[mi][0], kf0, s[mi][tt]);
        s[mi][tt] = MFMA16(qf[mi][1], kf1, s[mi][tt]);
      }
    }

    // --- softmax over t: no max-pass (logits small by construction) ---
    float linv[2][4];
#pragma unroll
    for (int mi = 0; mi < 2; mi++) {
#pragma unroll
      for (int r = 0; r < 4; r++) {
        float sum = 0.f;
#pragma unroll
        for (int tt = 0; tt < 5; tt++) {
          float e = __expf(s[mi][tt][r] * 0.125f);
          if (tt == 4 && l16 >= 13) e = 0.f;  // t = 64+l16 >= 77 masked
          s[mi][tt][r] = e;
          sum += e;
        }
#pragma unroll
        for (int off = 1; off < 16; off <<= 1) sum += __shfl_xor(sum, off, 16);
        linv[mi][r] = 1.f / sum;
      }
    }

    // --- P: C/D layout -> LDS -> A-operand layout ---
#pragma unroll
    for (int mi = 0; mi < 2; mi++)
#pragma unroll
      for (int tt = 0; tt < 5; tt++)
#pragma unroll
        for (int r = 0; r < 4; r++) {
          int row = mi * 16 + quad * 4 + r, col = tt * 16 + l16;
          pl[row * 104 + col] = (bf16)s[mi][tt][r];
        }
    __syncthreads();

    // --- O_n = P V  (Vt: d-major, t contiguous, zero-padded to 96) ---
    f32x4 pv[2][4];
#pragma unroll
    for (int mi = 0; mi < 2; mi++)
#pragma unroll
      for (int nt = 0; nt < 4; nt++)
#pragma unroll
        for (int r = 0; r < 4; r++) pv[mi][nt][r] = 0.f;

#pragma unroll
    for (int ks = 0; ks < 3; ks++) {
      bf16x8 pf[2];
#pragma unroll
      for (int mi = 0; mi < 2; mi++)
        pf[mi] = *(const bf16x8*)(pl + (mi * 16 + l16) * 104 + ks * 32 + quad * 8);
#pragma unroll
      for (int nt = 0; nt < 4; nt++) {
        bf16x8 vf = *(const bf16x8*)(Vb + (size_t)(nt * 16 + l16) * 96 + ks * 32 + quad * 8);
#pragma unroll
        for (int mi = 0; mi < 2; mi++) pv[mi][nt] = MFMA16(pf[mi], vf, pv[mi][nt]);
      }
    }
    __syncthreads();  // LDS WAR vs next n (uniform across waves)

    // --- masked accumulate over n ---
#pragma unroll
    for (int mi = 0; mi < 2; mi++)
#pragma unroll
      for (int r = 0; r < 4; r++) {
        int row = qrow0 + mi * 16 + quad * 4 + r;
        float rg = (mask[(size_t)bn * 4096 + row] > 0.5f) ? 1.f : 0.f;
        float f = rg * linv[mi][r];
#pragma unroll
        for (int nt = 0; nt < 4; nt++) oacc[mi][nt][r] += pv[mi][nt][r] * f;
      }
  }

  // overwrite this wave's own Q tile with the masked attention sum
#pragma unroll
  for (int mi = 0; mi < 2; mi++)
#pragma unroll
    for (int r = 0; r < 4; r++) {
      size_t row = (size_t)(b * 4096 + qrow0 + mi * 16 + quad * 4 + r);
#pragma unroll
      for (int nt = 0; nt < 4; nt++)
        QO[row * 1024 + h * 64 + nt * 16 + l16] = oacc[mi][nt][r];
    }
}

// ---------------------------------------------------------------------------
// In-place fp32: QO = QO @ WoT^T + cover*bo + (1-cover)*null + x  (8192x1024)
// ---------------------------------------------------------------------------
__global__ __launch_bounds__(512) void gemm_wo_ep(float* QO,
                                                  const bf16* __restrict__ WoT,
                                                  const float* __restrict__ x,
                                                  const float* __restrict__ bo,
                                                  const float* __restrict__ nullf,
                                                  const float* __restrict__ cover) {
  __shared__ __align__(16) bf16 lds_a[32 * 32 * 32];  // [kt][row][kin]
  const int tid = threadIdx.x;
  const int lane = tid & 63, wv = tid >> 6;
  const int l16 = lane & 15, quad = lane >> 4;
  const int m0 = blockIdx.x * 32;

#pragma unroll
  for (int c = 0; c < 16; c++) {
    int ch = c * 512 + tid;
    int row = ch >> 8;
    int pos4 = (ch & 255) * 4;
    int kt = pos4 >> 5, kin = pos4 & 31;
    f32x4 v = *(const f32x4*)(QO + (size_t)(m0 + row) * 1024 + pos4);
    bf16x4 w;
    w[0] = (bf16)v[0]; w[1] = (bf16)v[1]; w[2] = (bf16)v[2]; w[3] = (bf16)v[3];
    *(bf16x4*)(lds_a + kt * 1024 + row * 32 + kin) = w;
  }
  __syncthreads();

  const int n0 = wv * 128;
  f32x4 acc[2][8];
#pragma unroll
  for (int mi = 0; mi < 2; mi++)
#pragma unroll
    for (int ni = 0; ni < 8; ni++)
#pragma unroll
      for (int r = 0; r < 4; r++) acc[mi][ni][r] = 0.f;

  for (int kt = 0; kt < 32; kt++) {
    bf16x8 a[2];
#pragma unroll
    for (int mi = 0; mi < 2; mi++)
      a[mi] = *(const bf16x8*)(lds_a + kt * 1024 + (mi * 16 + l16) * 32 + quad * 8);
    bf16x8 bfr[8];
#pragma unroll
    for (int ni = 0; ni < 8; ni++)
      bfr[ni] = *(const bf16x8*)(WoT + (size_t)(n0 + ni * 16 + l16) * 1024 + kt * 32 + quad * 8);
#pragma unroll
    for (int mi = 0; mi < 2; mi++)
#pragma unroll
      for (int ni = 0; ni < 8; ni++) acc[mi][ni] = MFMA16(a[mi], bfr[ni], acc[mi][ni]);
  }

#pragma unroll
  for (int mi = 0; mi < 2; mi++)
#pragma unroll
    for (int r = 0; r < 4; r++) {
      int row = m0 + mi * 16 + quad * 4 + r;
      float cv = cover[row];
#pragma unroll
      for (int ni = 0; ni < 8; ni++) {
        int col = n0 + ni * 16 + l16;
        float v = acc[mi][ni][r] + cv * bo[col] + (1.f - cv) * nullf[col] +
                  x[(size_t)row * 1024 + col];
        QO[(size_t)row * 1024 + col] = v;
      }
    }
}

// ---------------------------------------------------------------------------
extern "C" void kernel_launch(void* const* d_in, const int* in_sizes, int n_in,
                              void* d_out, int out_size, void* d_ws, size_t ws_size,
                              hipStream_t stream) {
  const float* x     = (const float*)d_in[0];
  const float* masks = (const float*)d_in[1];
  const float* text  = (const float*)d_in[2];
  const float* Wq    = (const float*)d_in[3];
  const float* Wk    = (const float*)d_in[4];
  const float* Wv    = (const float*)d_in[5];
  const float* Wo    = (const float*)d_in[6];
  const float* bo    = (const float*)d_in[7];
  const float* nullf = (const float*)d_in[8];
  float* out = (float*)d_out;

  // workspace: 13,139,968 bytes
  bf16* ws  = (bf16*)d_ws;
  bf16* WqT = ws;                  // 1024*1024
  bf16* WkT = WqT + 1048576;       // 1024*768
  bf16* WvT = WkT + 786432;        // 1024*768
  bf16* WoT = WvT + 786432;        // 1024*1024
  bf16* Kp  = WoT + 1048576;       // 16*80*1024
  bf16* Vt  = Kp + 1310720;        // 16*1024*96
  float* cover = (float*)(Vt + 1572864);  // 8192 f32

  transpose_cvt_k<<<dim3(32, 32), 256, 0, stream>>>(Wq, WqT, 1024, 1024);
  transpose_cvt_k<<<dim3(32, 24), 256, 0, stream>>>(Wk, WkT, 768, 1024);
  transpose_cvt_k<<<dim3(32, 24), 256, 0, stream>>>(Wv, WvT, 768, 1024);
  transpose_cvt_k<<<dim3(32, 32), 256, 0, stream>>>(Wo, WoT, 1024, 1024);

  gemm_q_kernel<<<dim3(8, 64), 256, 0, stream>>>(x, WqT, out, 8192, 1024, 1024);
  gemm_k_pad<<<dim3(8, 16), 256, 0, stream>>>(text, WkT, Kp);
  gemm_v_t<<<dim3(8, 16), 256, 0, stream>>>(text, WvT, Vt);

  cover_kernel<<<32, 256, 0, stream>>>(masks, cover);
  attn_kernel<<<1024, 256, 0, stream>>>(out, Kp, Vt, masks);

  gemm_wo_ep<<<256, 512, 0, stream>>>(out, WoT, x, bo, nullf, cover);
}

// Round 6
// 410.667 us; speedup vs baseline: 1.1547x; 1.1547x over previous
//
#include <hip/hip_runtime.h>

// ---------------------------------------------------------------------------
// RegionalCrossAttention on MI355X (gfx950).  fp32 in / fp32 out.
// B=2, n=8, L=4096, Lt=77, d=1024, ctx=768, H=16 heads x 64.
//
//   Q = x@Wq once per batch  -> fp32, stored in d_out (LDS-staged GEMM).
//   K -> Kp[bn][80][1024]   (bf16, t padded to 80 with zero rows)
//   V -> Vt[bn][1024][96]   (bf16, TRANSPOSED, t padded to 96 with zeros)
//   attn IN-PLACE on d_out. Round 6: computes S^T = K*Q^T (lane=m, regs=t in
//     C/D layout) -> softmax reduce = 2 shuffles, P store = 10 vector b64s;
//     NO barriers in the n-loop (per-wave-private P; DS ops are in-order
//     per wave) -> no vmcnt(0) drain per iteration.
//   out = ACC@Wo + cover*bo + (1-cover)*null + x, IN-PLACE on d_out.
//
// Workspace: 13.14 MB.
// ---------------------------------------------------------------------------

typedef __bf16 bf16;
typedef __bf16 bf16x8 __attribute__((ext_vector_type(8)));
typedef __bf16 bf16x4 __attribute__((ext_vector_type(4)));
typedef float  f32x4  __attribute__((ext_vector_type(4)));

#define MFMA16(a, b, c) __builtin_amdgcn_mfma_f32_16x16x32_bf16((a), (b), (c), 0, 0, 0)

// v_mfma_f32_16x16x32_bf16 layouts (HW-verified, learn_hip m89/m120):
//   A: lane holds A[m = lane&15][k = 8*(lane>>4) + j], j=0..7
//   B: lane holds B[k = 8*(lane>>4) + j][n = lane&15]
//   D: lane,reg r holds D[m = 4*(lane>>4) + r][n = lane&15]

__device__ inline bf16x8 cvt8(const float* p) {
  f32x4 a = *(const f32x4*)p;
  f32x4 b = *(const f32x4*)(p + 4);
  bf16x8 r;
  r[0] = (bf16)a[0]; r[1] = (bf16)a[1]; r[2] = (bf16)a[2]; r[3] = (bf16)a[3];
  r[4] = (bf16)b[0]; r[5] = (bf16)b[1]; r[6] = (bf16)b[2]; r[7] = (bf16)b[3];
  return r;
}

// ---------------------------------------------------------------------------
// Transpose + downcast: out_bf16[c][r] = (bf16)in_f32[r][c].  R,C mult of 32.
// ---------------------------------------------------------------------------
__global__ __launch_bounds__(256) void transpose_cvt_k(const float* __restrict__ in,
                                                       bf16* __restrict__ out,
                                                       int R, int C) {
  __shared__ bf16 tile[32][33];
  int tx = threadIdx.x & 31, ty = threadIdx.x >> 5;
  int bx = blockIdx.x, by = blockIdx.y;
  int c = bx * 32 + tx;
#pragma unroll
  for (int i = 0; i < 32; i += 8) {
    int r = by * 32 + ty + i;
    tile[ty + i][tx] = (bf16)in[(size_t)r * C + c];
  }
  __syncthreads();
#pragma unroll
  for (int i = 0; i < 32; i += 8) {
    out[(size_t)(bx * 32 + ty + i) * R + by * 32 + tx] = tile[tx][ty + i];
  }
}

// ---------------------------------------------------------------------------
// Q GEMM: C_f32[8192,1024] = x_f32 @ WqT^T.  64m x 256n block tile, BK=32,
// A staged in double-buffered LDS (cvt once per element), 4 waves (64n each).
// One barrier per k-step; A-prefetch rides across it in VGPRs.
// ---------------------------------------------------------------------------
__global__ __launch_bounds__(256) void gemm_q_kernel(const float* __restrict__ A,
                                                     const bf16* __restrict__ BT,
                                                     float* __restrict__ C) {
  __shared__ __align__(16) bf16 asA[2][64 * 32];
  const int tid = threadIdx.x;
  const int lane = tid & 63, wave = tid >> 6;
  const int l16 = lane & 15, quad = lane >> 4;
  const int m0 = blockIdx.y * 64;
  const int n0 = blockIdx.x * 256 + wave * 64;
  const int srow = tid >> 2, scol = (tid & 3) * 8;
  const float* aptr = A + (size_t)(m0 + srow) * 1024 + scol;

  // stage kt=0
  *(bf16x8*)(&asA[0][srow * 32 + scol]) = cvt8(aptr);

  f32x4 acc[4][4];
#pragma unroll
  for (int i = 0; i < 4; i++)
#pragma unroll
    for (int j = 0; j < 4; j++)
#pragma unroll
      for (int r = 0; r < 4; r++) acc[i][j][r] = 0.f;

  for (int kt = 0; kt < 32; kt++) {
    bf16x8 wnext;
    if (kt + 1 < 32) wnext = cvt8(aptr + (kt + 1) * 32);
    __syncthreads();  // asA[kt&1] ready
    const bf16* ab = &asA[kt & 1][0];
    bf16x8 a[4], b[4];
#pragma unroll
    for (int mi = 0; mi < 4; mi++)
      a[mi] = *(const bf16x8*)(ab + (mi * 16 + l16) * 32 + quad * 8);
#pragma unroll
    for (int ni = 0; ni < 4; ni++)
      b[ni] = *(const bf16x8*)(BT + (size_t)(n0 + ni * 16 + l16) * 1024 + kt * 32 + quad * 8);
#pragma unroll
    for (int mi = 0; mi < 4; mi++)
#pragma unroll
      for (int ni = 0; ni < 4; ni++) acc[mi][ni] = MFMA16(a[mi], b[ni], acc[mi][ni]);
    if (kt + 1 < 32)
      *(bf16x8*)(&asA[(kt + 1) & 1][srow * 32 + scol]) = wnext;
  }

#pragma unroll
  for (int mi = 0; mi < 4; mi++)
#pragma unroll
    for (int r = 0; r < 4; r++) {
      int row = m0 + mi * 16 + quad * 4 + r;
#pragma unroll
      for (int ni = 0; ni < 4; ni++)
        C[(size_t)row * 1024 + n0 + ni * 16 + l16] = acc[mi][ni][r];
    }
}

// ---------------------------------------------------------------------------
// K GEMM with padded store: Kp[bn][80][1024] bf16; t rows 77..79 zeroed.
// ---------------------------------------------------------------------------
__global__ __launch_bounds__(256) void gemm_k_pad(const float* __restrict__ text,
                                                  const bf16* __restrict__ WkT,
                                                  bf16* __restrict__ Kp) {
  const int tid = threadIdx.x;
  const int lane = tid & 63, wave = tid >> 6;
  const int l16 = lane & 15, quad = lane >> 4;
  const int m0 = (wave >> 1) * 64;
  const int n0 = blockIdx.x * 128 + (wave & 1) * 64;
  const int bn = blockIdx.y;
  const float* A = text + (size_t)bn * 77 * 768;
  bf16* dst = Kp + (size_t)bn * 80 * 1024;

  f32x4 acc[4][4];
#pragma unroll
  for (int i = 0; i < 4; i++)
#pragma unroll
    for (int j = 0; j < 4; j++)
#pragma unroll
      for (int r = 0; r < 4; r++) acc[i][j][r] = 0.f;

  for (int k0 = 0; k0 < 768; k0 += 32) {
    bf16x8 a[4], b[4];
#pragma unroll
    for (int mi = 0; mi < 4; mi++) {
      int row = m0 + mi * 16 + l16;
      if (row >= 77) row = 76;  // safe read; store guarded
      a[mi] = cvt8(A + (size_t)row * 768 + k0 + quad * 8);
    }
#pragma unroll
    for (int ni = 0; ni < 4; ni++)
      b[ni] = *(const bf16x8*)(WkT + (size_t)(n0 + ni * 16 + l16) * 768 + k0 + quad * 8);
#pragma unroll
    for (int mi = 0; mi < 4; mi++)
#pragma unroll
      for (int ni = 0; ni < 4; ni++) acc[mi][ni] = MFMA16(a[mi], b[ni], acc[mi][ni]);
  }

#pragma unroll
  for (int mi = 0; mi < 4; mi++)
#pragma unroll
    for (int r = 0; r < 4; r++) {
      int t = m0 + mi * 16 + quad * 4 + r;
      if (t < 77) {
#pragma unroll
        for (int ni = 0; ni < 4; ni++)
          dst[(size_t)t * 1024 + n0 + ni * 16 + l16] = (bf16)acc[mi][ni][r];
      } else if (t < 80) {
#pragma unroll
        for (int ni = 0; ni < 4; ni++)
          dst[(size_t)t * 1024 + n0 + ni * 16 + l16] = (bf16)0.f;
      }
    }
}

// ---------------------------------------------------------------------------
// V GEMM with TRANSPOSED padded store: Vt[bn][1024][96] bf16 (t contiguous),
// t in [77,96) zeroed.
// ---------------------------------------------------------------------------
__global__ __launch_bounds__(256) void gemm_v_t(const float* __restrict__ text,
                                                const bf16* __restrict__ WvT,
                                                bf16* __restrict__ Vt) {
  const int tid = threadIdx.x;
  const int lane = tid & 63, wave = tid >> 6;
  const int l16 = lane & 15, quad = lane >> 4;
  const int m0 = (wave >> 1) * 64;
  const int n0 = blockIdx.x * 128 + (wave & 1) * 64;
  const int bn = blockIdx.y;
  const float* A = text + (size_t)bn * 77 * 768;
  bf16* dst = Vt + (size_t)bn * 1024 * 96;

  f32x4 acc[4][4];
#pragma unroll
  for (int i = 0; i < 4; i++)
#pragma unroll
    for (int j = 0; j < 4; j++)
#pragma unroll
      for (int r = 0; r < 4; r++) acc[i][j][r] = 0.f;

  for (int k0 = 0; k0 < 768; k0 += 32) {
    bf16x8 a[4], b[4];
#pragma unroll
    for (int mi = 0; mi < 4; mi++) {
      int row = m0 + mi * 16 + l16;
      if (row >= 77) row = 76;
      a[mi] = cvt8(A + (size_t)row * 768 + k0 + quad * 8);
    }
#pragma unroll
    for (int ni = 0; ni < 4; ni++)
      b[ni] = *(const bf16x8*)(WvT + (size_t)(n0 + ni * 16 + l16) * 768 + k0 + quad * 8);
#pragma unroll
    for (int mi = 0; mi < 4; mi++)
#pragma unroll
      for (int ni = 0; ni < 4; ni++) acc[mi][ni] = MFMA16(a[mi], b[ni], acc[mi][ni]);
  }

#pragma unroll
  for (int mi = 0; mi < 4; mi++) {
    int t0 = m0 + mi * 16 + quad * 4;
#pragma unroll
    for (int ni = 0; ni < 4; ni++) {
      int col = n0 + ni * 16 + l16;
      bf16* cbase = dst + (size_t)col * 96;
      if (t0 + 3 < 77) {
        bf16x4 w;
        w[0] = (bf16)acc[mi][ni][0]; w[1] = (bf16)acc[mi][ni][1];
        w[2] = (bf16)acc[mi][ni][2]; w[3] = (bf16)acc[mi][ni][3];
        *(bf16x4*)(cbase + t0) = w;
      } else {
#pragma unroll
        for (int r = 0; r < 4; r++) {
          int t = t0 + r;
          if (t < 77)      cbase[t] = (bf16)acc[mi][ni][r];
          else if (t < 96) cbase[t] = (bf16)0.f;
        }
      }
    }
  }
}

// ---------------------------------------------------------------------------
// cover[b,l] = sum_n (mask[b,n,l] > 0.5)
// ---------------------------------------------------------------------------
__global__ __launch_bounds__(256) void cover_kernel(const float* __restrict__ mask,
                                                    float* __restrict__ cover) {
  int tid = blockIdx.x * 256 + threadIdx.x;
  int b = tid >> 12, l = tid & 4095;
  float c = 0.f;
#pragma unroll
  for (int n = 0; n < 8; n++)
    c += (mask[(size_t)(b * 8 + n) * 4096 + l] > 0.5f) ? 1.f : 0.f;
  cover[tid] = c;
}

// ---------------------------------------------------------------------------
// Attention v3, IN-PLACE on fp32 QO. 4 waves/block (wave = one 32-row
// q-block of head h). S^T = K*Q^T: C/D layout puts lane=m-col, regs=t-row:
//   - softmax sum over t = in-lane adds + 2 shuffle rounds (xor 16, 32)
//   - normalized P[m][t] stored with bf16x4 vector writes (r = consecutive t)
// NO __syncthreads in the n-loop: P buffer is wave-private and DS ops are
// in-order per wave -> no vmcnt/lgkm drain, loads overlap across iterations.
// ---------------------------------------------------------------------------
__global__ __launch_bounds__(256) void attn_kernel(float* QO,                    // (B*4096,1024)
                                                   const bf16* __restrict__ Kp,  // (16,80,1024)
                                                   const bf16* __restrict__ Vt,  // (16,1024,96)
                                                   const float* __restrict__ mask) { // (2,8,4096)
  __shared__ __align__(16) bf16 p_lds[4][32 * 104];
  const int tid = threadIdx.x;
  const int lane = tid & 63, wave = tid >> 6;
  const int l16 = lane & 15, quad = lane >> 4;
  const int bid = blockIdx.x;            // 1024 blocks
  const int qg = bid & 31;
  const int h = (bid >> 5) & 15;
  const int b = bid >> 9;
  const int qrow0 = qg * 128 + wave * 32;
  bf16* pl = &p_lds[wave][0];

  // zero PV padding cols 80..95 (own wave's region; in-order DS => no barrier)
  for (int i = lane; i < 32 * 16; i += 64) {
    int r = i >> 4, c = 80 + (i & 15);
    pl[r * 104 + c] = (bf16)0.f;
  }

  // Q fragment: serves as B-operand of S^T = K*Q^T (same register content
  // as the A-operand of Q*K^T).
  bf16x8 qf[2][2];
#pragma unroll
  for (int mi = 0; mi < 2; mi++)
#pragma unroll
    for (int ks = 0; ks < 2; ks++)
      qf[mi][ks] = cvt8(QO + (size_t)(b * 4096 + qrow0 + mi * 16 + l16) * 1024 +
                        h * 64 + ks * 32 + quad * 8);

  f32x4 oacc[2][4];
#pragma unroll
  for (int mi = 0; mi < 2; mi++)
#pragma unroll
    for (int nt = 0; nt < 4; nt++)
#pragma unroll
      for (int r = 0; r < 4; r++) oacc[mi][nt][r] = 0.f;

  for (int n = 0; n < 8; n++) {
    const int bn = b * 8 + n;
    const bf16* Kb = Kp + (size_t)bn * 80 * 1024 + h * 64;
    const bf16* Vb = Vt + (size_t)bn * 1024 * 96 + (size_t)h * 64 * 96;

    // --- S^T[t][m] = K Q^T:  A = K-frag (lane=t-row), B = Q-frag (lane=m) ---
    // C/D: lane l16 = m, row t = tt*16 + quad*4 + r
    f32x4 s[2][5];
#pragma unroll
    for (int mi = 0; mi < 2; mi++)
#pragma unroll
      for (int tt = 0; tt < 5; tt++)
#pragma unroll
        for (int r = 0; r < 4; r++) s[mi][tt][r] = 0.f;

#pragma unroll
    for (int tt = 0; tt < 5; tt++) {
      int t = tt * 16 + l16;
      bf16x8 kf0 = *(const bf16x8*)(Kb + (size_t)t * 1024 + quad * 8);
      bf16x8 kf1 = *(const bf16x8*)(Kb + (size_t)t * 1024 + 32 + quad * 8);
#pragma unroll
      for (int mi = 0; mi < 2; mi++) {
        s[mi][tt] = MFMA16(kf0, qf[mi][0], s[mi][tt]);
        s[mi][tt] = MFMA16(kf1, qf[mi][1], s[mi][tt]);
      }
    }

    // --- softmax over t, then store normalized P[m][t] to LDS ---
    // lane's m = mi*16 + l16; its t values: tt*16 + quad*4 + r
#pragma unroll
    for (int mi = 0; mi < 2; mi++) {
      float sum = 0.f;
#pragma unroll
      for (int tt = 0; tt < 5; tt++) {
#pragma unroll
        for (int r = 0; r < 4; r++) {
          float e = __expf(s[mi][tt][r] * 0.125f);
          if (tt == 4 && quad * 4 + r >= 13) e = 0.f;  // t >= 77 masked
          s[mi][tt][r] = e;
          sum += e;
        }
      }
      sum += __shfl_xor(sum, 16);
      sum += __shfl_xor(sum, 32);
      float inv = 1.f / sum;
#pragma unroll
      for (int tt = 0; tt < 5; tt++) {
        bf16x4 w;
#pragma unroll
        for (int r = 0; r < 4; r++) w[r] = (bf16)(s[mi][tt][r] * inv);
        *(bf16x4*)(pl + (mi * 16 + l16) * 104 + tt * 16 + quad * 4) = w;
      }
    }

    // --- O_n = P V  (P from wave-private LDS; Vt d-major, t-contiguous) ---
    f32x4 pv[2][4];
#pragma unroll
    for (int mi = 0; mi < 2; mi++)
#pragma unroll
      for (int nt = 0; nt < 4; nt++)
#pragma unroll
        for (int r = 0; r < 4; r++) pv[mi][nt][r] = 0.f;

#pragma unroll
    for (int ks = 0; ks < 3; ks++) {
      bf16x8 pf[2];
#pragma unroll
      for (int mi = 0; mi < 2; mi++)
        pf[mi] = *(const bf16x8*)(pl + (mi * 16 + l16) * 104 + ks * 32 + quad * 8);
#pragma unroll
      for (int nt = 0; nt < 4; nt++) {
        bf16x8 vf = *(const bf16x8*)(Vb + (size_t)(nt * 16 + l16) * 96 + ks * 32 + quad * 8);
#pragma unroll
        for (int mi = 0; mi < 2; mi++) pv[mi][nt] = MFMA16(pf[mi], vf, pv[mi][nt]);
      }
    }

    // --- region-masked accumulate (P already normalized) ---
#pragma unroll
    for (int mi = 0; mi < 2; mi++)
#pragma unroll
      for (int r = 0; r < 4; r++) {
        int row = qrow0 + mi * 16 + quad * 4 + r;
        float rg = (mask[(size_t)bn * 4096 + row] > 0.5f) ? 1.f : 0.f;
#pragma unroll
        for (int nt = 0; nt < 4; nt++) oacc[mi][nt][r] += pv[mi][nt][r] * rg;
      }
  }

  // overwrite this wave's own Q tile with the masked attention sum
#pragma unroll
  for (int mi = 0; mi < 2; mi++)
#pragma unroll
    for (int r = 0; r < 4; r++) {
      size_t row = (size_t)(b * 4096 + qrow0 + mi * 16 + quad * 4 + r);
#pragma unroll
      for (int nt = 0; nt < 4; nt++)
        QO[row * 1024 + h * 64 + nt * 16 + l16] = oacc[mi][nt][r];
    }
}

// ---------------------------------------------------------------------------
// In-place fp32: QO = QO @ WoT^T + cover*bo + (1-cover)*null + x  (8192x1024)
// ---------------------------------------------------------------------------
__global__ __launch_bounds__(512) void gemm_wo_ep(float* QO,
                                                  const bf16* __restrict__ WoT,
                                                  const float* __restrict__ x,
                                                  const float* __restrict__ bo,
                                                  const float* __restrict__ nullf,
                                                  const float* __restrict__ cover) {
  __shared__ __align__(16) bf16 lds_a[32 * 32 * 32];  // [kt][row][kin]
  const int tid = threadIdx.x;
  const int lane = tid & 63, wv = tid >> 6;
  const int l16 = lane & 15, quad = lane >> 4;
  const int m0 = blockIdx.x * 32;

#pragma unroll
  for (int c = 0; c < 16; c++) {
    int ch = c * 512 + tid;
    int row = ch >> 8;
    int pos4 = (ch & 255) * 4;
    int kt = pos4 >> 5, kin = pos4 & 31;
    f32x4 v = *(const f32x4*)(QO + (size_t)(m0 + row) * 1024 + pos4);
    bf16x4 w;
    w[0] = (bf16)v[0]; w[1] = (bf16)v[1]; w[2] = (bf16)v[2]; w[3] = (bf16)v[3];
    *(bf16x4*)(lds_a + kt * 1024 + row * 32 + kin) = w;
  }
  __syncthreads();

  const int n0 = wv * 128;
  f32x4 acc[2][8];
#pragma unroll
  for (int mi = 0; mi < 2; mi++)
#pragma unroll
    for (int ni = 0; ni < 8; ni++)
#pragma unroll
      for (int r = 0; r < 4; r++) acc[mi][ni][r] = 0.f;

  for (int kt = 0; kt < 32; kt++) {
    bf16x8 a[2];
#pragma unroll
    for (int mi = 0; mi < 2; mi++)
      a[mi] = *(const bf16x8*)(lds_a + kt * 1024 + (mi * 16 + l16) * 32 + quad * 8);
    bf16x8 bfr[8];
#pragma unroll
    for (int ni = 0; ni < 8; ni++)
      bfr[ni] = *(const bf16x8*)(WoT + (size_t)(n0 + ni * 16 + l16) * 1024 + kt * 32 + quad * 8);
#pragma unroll
    for (int mi = 0; mi < 2; mi++)
#pragma unroll
      for (int ni = 0; ni < 8; ni++) acc[mi][ni] = MFMA16(a[mi], bfr[ni], acc[mi][ni]);
  }

#pragma unroll
  for (int mi = 0; mi < 2; mi++)
#pragma unroll
    for (int r = 0; r < 4; r++) {
      int row = m0 + mi * 16 + quad * 4 + r;
      float cv = cover[row];
#pragma unroll
      for (int ni = 0; ni < 8; ni++) {
        int col = n0 + ni * 16 + l16;
        float v = acc[mi][ni][r] + cv * bo[col] + (1.f - cv) * nullf[col] +
                  x[(size_t)row * 1024 + col];
        QO[(size_t)row * 1024 + col] = v;
      }
    }
}

// ---------------------------------------------------------------------------
extern "C" void kernel_launch(void* const* d_in, const int* in_sizes, int n_in,
                              void* d_out, int out_size, void* d_ws, size_t ws_size,
                              hipStream_t stream) {
  const float* x     = (const float*)d_in[0];
  const float* masks = (const float*)d_in[1];
  const float* text  = (const float*)d_in[2];
  const float* Wq    = (const float*)d_in[3];
  const float* Wk    = (const float*)d_in[4];
  const float* Wv    = (const float*)d_in[5];
  const float* Wo    = (const float*)d_in[6];
  const float* bo    = (const float*)d_in[7];
  const float* nullf = (const float*)d_in[8];
  float* out = (float*)d_out;

  // workspace: 13,139,968 bytes
  bf16* ws  = (bf16*)d_ws;
  bf16* WqT = ws;                  // 1024*1024
  bf16* WkT = WqT + 1048576;       // 1024*768
  bf16* WvT = WkT + 786432;        // 1024*768
  bf16* WoT = WvT + 786432;        // 1024*1024
  bf16* Kp  = WoT + 1048576;       // 16*80*1024
  bf16* Vt  = Kp + 1310720;        // 16*1024*96
  float* cover = (float*)(Vt + 1572864);  // 8192 f32

  transpose_cvt_k<<<dim3(32, 32), 256, 0, stream>>>(Wq, WqT, 1024, 1024);
  transpose_cvt_k<<<dim3(32, 24), 256, 0, stream>>>(Wk, WkT, 768, 1024);
  transpose_cvt_k<<<dim3(32, 24), 256, 0, stream>>>(Wv, WvT, 768, 1024);
  transpose_cvt_k<<<dim3(32, 32), 256, 0, stream>>>(Wo, WoT, 1024, 1024);

  gemm_q_kernel<<<dim3(4, 128), 256, 0, stream>>>(x, WqT, out);
  gemm_k_pad<<<dim3(8, 16), 256, 0, stream>>>(text, WkT, Kp);
  gemm_v_t<<<dim3(8, 16), 256, 0, stream>>>(text, WvT, Vt);

  cover_kernel<<<32, 256, 0, stream>>>(masks, cover);
  attn_kernel<<<1024, 256, 0, stream>>>(out, Kp, Vt, masks);

  gemm_wo_ep<<<256, 512, 0, stream>>>(out, WoT, x, bo, nullf, cover);
}

// Round 7
// 390.795 us; speedup vs baseline: 1.2134x; 1.0509x over previous
//
#include <hip/hip_runtime.h>

// ---------------------------------------------------------------------------
// RegionalCrossAttention on MI355X (gfx950).  fp32 in / fp32 out.
// B=2, n=8, L=4096, Lt=77, d=1024, ctx=768, H=16 heads x 64.
//
//   Q = x@Wq once per batch  -> fp32, stored in d_out (LDS-staged GEMM).
//   K -> Kp[bn][80][1024]   (bf16, t padded to 80 with zero rows)
//   V -> Vt[bn][1024][96]   (bf16, TRANSPOSED, t padded to 96 with zeros)
//   attn v5 IN-PLACE on d_out:
//     - block = (b,h,128 q-rows), 4 waves x 32 rows
//     - K/V tiles staged to padded LDS once per block per n (4x VMEM cut;
//       16-segment global gathers -> conflict-free ds_read_b128)
//     - S^T = K*Q^T (softmax reduce = 2 shuffles, vector P stores)
//     - region-mask * 1/sum folded into P; PV accumulates into oacc (C-op)
//     - region masks preloaded into registers
//   out = ACC@Wo + cover*bo + (1-cover)*null + x, IN-PLACE on d_out.
//
// Workspace: 13.14 MB.
// ---------------------------------------------------------------------------

typedef __bf16 bf16;
typedef __bf16 bf16x8 __attribute__((ext_vector_type(8)));
typedef __bf16 bf16x4 __attribute__((ext_vector_type(4)));
typedef float  f32x4  __attribute__((ext_vector_type(4)));

#define MFMA16(a, b, c) __builtin_amdgcn_mfma_f32_16x16x32_bf16((a), (b), (c), 0, 0, 0)

// v_mfma_f32_16x16x32_bf16 layouts (HW-verified, learn_hip m89/m120):
//   A: lane holds A[m = lane&15][k = 8*(lane>>4) + j], j=0..7
//   B: lane holds B[k = 8*(lane>>4) + j][n = lane&15]
//   D: lane,reg r holds D[m = 4*(lane>>4) + r][n = lane&15]

__device__ inline bf16x8 cvt8(const float* p) {
  f32x4 a = *(const f32x4*)p;
  f32x4 b = *(const f32x4*)(p + 4);
  bf16x8 r;
  r[0] = (bf16)a[0]; r[1] = (bf16)a[1]; r[2] = (bf16)a[2]; r[3] = (bf16)a[3];
  r[4] = (bf16)b[0]; r[5] = (bf16)b[1]; r[6] = (bf16)b[2]; r[7] = (bf16)b[3];
  return r;
}

// ---------------------------------------------------------------------------
// Transpose + downcast: out_bf16[c][r] = (bf16)in_f32[r][c].  R,C mult of 32.
// ---------------------------------------------------------------------------
__global__ __launch_bounds__(256) void transpose_cvt_k(const float* __restrict__ in,
                                                       bf16* __restrict__ out,
                                                       int R, int C) {
  __shared__ bf16 tile[32][33];
  int tx = threadIdx.x & 31, ty = threadIdx.x >> 5;
  int bx = blockIdx.x, by = blockIdx.y;
  int c = bx * 32 + tx;
#pragma unroll
  for (int i = 0; i < 32; i += 8) {
    int r = by * 32 + ty + i;
    tile[ty + i][tx] = (bf16)in[(size_t)r * C + c];
  }
  __syncthreads();
#pragma unroll
  for (int i = 0; i < 32; i += 8) {
    out[(size_t)(bx * 32 + ty + i) * R + by * 32 + tx] = tile[tx][ty + i];
  }
}

// ---------------------------------------------------------------------------
// Q GEMM: C_f32[8192,1024] = x_f32 @ WqT^T.  64m x 256n block tile, BK=32,
// A staged in double-buffered LDS, 4 waves (64n each).
// ---------------------------------------------------------------------------
__global__ __launch_bounds__(256) void gemm_q_kernel(const float* __restrict__ A,
                                                     const bf16* __restrict__ BT,
                                                     float* __restrict__ C) {
  __shared__ __align__(16) bf16 asA[2][64 * 32];
  const int tid = threadIdx.x;
  const int lane = tid & 63, wave = tid >> 6;
  const int l16 = lane & 15, quad = lane >> 4;
  const int m0 = blockIdx.y * 64;
  const int n0 = blockIdx.x * 256 + wave * 64;
  const int srow = tid >> 2, scol = (tid & 3) * 8;
  const float* aptr = A + (size_t)(m0 + srow) * 1024 + scol;

  *(bf16x8*)(&asA[0][srow * 32 + scol]) = cvt8(aptr);

  f32x4 acc[4][4];
#pragma unroll
  for (int i = 0; i < 4; i++)
#pragma unroll
    for (int j = 0; j < 4; j++)
#pragma unroll
      for (int r = 0; r < 4; r++) acc[i][j][r] = 0.f;

  for (int kt = 0; kt < 32; kt++) {
    bf16x8 wnext;
    if (kt + 1 < 32) wnext = cvt8(aptr + (kt + 1) * 32);
    __syncthreads();
    const bf16* ab = &asA[kt & 1][0];
    bf16x8 a[4], b[4];
#pragma unroll
    for (int mi = 0; mi < 4; mi++)
      a[mi] = *(const bf16x8*)(ab + (mi * 16 + l16) * 32 + quad * 8);
#pragma unroll
    for (int ni = 0; ni < 4; ni++)
      b[ni] = *(const bf16x8*)(BT + (size_t)(n0 + ni * 16 + l16) * 1024 + kt * 32 + quad * 8);
#pragma unroll
    for (int mi = 0; mi < 4; mi++)
#pragma unroll
      for (int ni = 0; ni < 4; ni++) acc[mi][ni] = MFMA16(a[mi], b[ni], acc[mi][ni]);
    if (kt + 1 < 32)
      *(bf16x8*)(&asA[(kt + 1) & 1][srow * 32 + scol]) = wnext;
  }

#pragma unroll
  for (int mi = 0; mi < 4; mi++)
#pragma unroll
    for (int r = 0; r < 4; r++) {
      int row = m0 + mi * 16 + quad * 4 + r;
#pragma unroll
      for (int ni = 0; ni < 4; ni++)
        C[(size_t)row * 1024 + n0 + ni * 16 + l16] = acc[mi][ni][r];
    }
}

// ---------------------------------------------------------------------------
// K GEMM with padded store: Kp[bn][80][1024] bf16; t rows 77..79 zeroed.
// ---------------------------------------------------------------------------
__global__ __launch_bounds__(256) void gemm_k_pad(const float* __restrict__ text,
                                                  const bf16* __restrict__ WkT,
                                                  bf16* __restrict__ Kp) {
  const int tid = threadIdx.x;
  const int lane = tid & 63, wave = tid >> 6;
  const int l16 = lane & 15, quad = lane >> 4;
  const int m0 = (wave >> 1) * 64;
  const int n0 = blockIdx.x * 128 + (wave & 1) * 64;
  const int bn = blockIdx.y;
  const float* A = text + (size_t)bn * 77 * 768;
  bf16* dst = Kp + (size_t)bn * 80 * 1024;

  f32x4 acc[4][4];
#pragma unroll
  for (int i = 0; i < 4; i++)
#pragma unroll
    for (int j = 0; j < 4; j++)
#pragma unroll
      for (int r = 0; r < 4; r++) acc[i][j][r] = 0.f;

  for (int k0 = 0; k0 < 768; k0 += 32) {
    bf16x8 a[4], b[4];
#pragma unroll
    for (int mi = 0; mi < 4; mi++) {
      int row = m0 + mi * 16 + l16;
      if (row >= 77) row = 76;  // safe read; store guarded
      a[mi] = cvt8(A + (size_t)row * 768 + k0 + quad * 8);
    }
#pragma unroll
    for (int ni = 0; ni < 4; ni++)
      b[ni] = *(const bf16x8*)(WkT + (size_t)(n0 + ni * 16 + l16) * 768 + k0 + quad * 8);
#pragma unroll
    for (int mi = 0; mi < 4; mi++)
#pragma unroll
      for (int ni = 0; ni < 4; ni++) acc[mi][ni] = MFMA16(a[mi], b[ni], acc[mi][ni]);
  }

#pragma unroll
  for (int mi = 0; mi < 4; mi++)
#pragma unroll
    for (int r = 0; r < 4; r++) {
      int t = m0 + mi * 16 + quad * 4 + r;
      if (t < 77) {
#pragma unroll
        for (int ni = 0; ni < 4; ni++)
          dst[(size_t)t * 1024 + n0 + ni * 16 + l16] = (bf16)acc[mi][ni][r];
      } else if (t < 80) {
#pragma unroll
        for (int ni = 0; ni < 4; ni++)
          dst[(size_t)t * 1024 + n0 + ni * 16 + l16] = (bf16)0.f;
      }
    }
}

// ---------------------------------------------------------------------------
// V GEMM with TRANSPOSED padded store: Vt[bn][1024][96] bf16 (t contiguous),
// t in [77,96) zeroed.
// ---------------------------------------------------------------------------
__global__ __launch_bounds__(256) void gemm_v_t(const float* __restrict__ text,
                                                const bf16* __restrict__ WvT,
                                                bf16* __restrict__ Vt) {
  const int tid = threadIdx.x;
  const int lane = tid & 63, wave = tid >> 6;
  const int l16 = lane & 15, quad = lane >> 4;
  const int m0 = (wave >> 1) * 64;
  const int n0 = blockIdx.x * 128 + (wave & 1) * 64;
  const int bn = blockIdx.y;
  const float* A = text + (size_t)bn * 77 * 768;
  bf16* dst = Vt + (size_t)bn * 1024 * 96;

  f32x4 acc[4][4];
#pragma unroll
  for (int i = 0; i < 4; i++)
#pragma unroll
    for (int j = 0; j < 4; j++)
#pragma unroll
      for (int r = 0; r < 4; r++) acc[i][j][r] = 0.f;

  for (int k0 = 0; k0 < 768; k0 += 32) {
    bf16x8 a[4], b[4];
#pragma unroll
    for (int mi = 0; mi < 4; mi++) {
      int row = m0 + mi * 16 + l16;
      if (row >= 77) row = 76;
      a[mi] = cvt8(A + (size_t)row * 768 + k0 + quad * 8);
    }
#pragma unroll
    for (int ni = 0; ni < 4; ni++)
      b[ni] = *(const bf16x8*)(WvT + (size_t)(n0 + ni * 16 + l16) * 768 + k0 + quad * 8);
#pragma unroll
    for (int mi = 0; mi < 4; mi++)
#pragma unroll
      for (int ni = 0; ni < 4; ni++) acc[mi][ni] = MFMA16(a[mi], b[ni], acc[mi][ni]);
  }

#pragma unroll
  for (int mi = 0; mi < 4; mi++) {
    int t0 = m0 + mi * 16 + quad * 4;
#pragma unroll
    for (int ni = 0; ni < 4; ni++) {
      int col = n0 + ni * 16 + l16;
      bf16* cbase = dst + (size_t)col * 96;
      if (t0 + 3 < 77) {
        bf16x4 w;
        w[0] = (bf16)acc[mi][ni][0]; w[1] = (bf16)acc[mi][ni][1];
        w[2] = (bf16)acc[mi][ni][2]; w[3] = (bf16)acc[mi][ni][3];
        *(bf16x4*)(cbase + t0) = w;
      } else {
#pragma unroll
        for (int r = 0; r < 4; r++) {
          int t = t0 + r;
          if (t < 77)      cbase[t] = (bf16)acc[mi][ni][r];
          else if (t < 96) cbase[t] = (bf16)0.f;
        }
      }
    }
  }
}

// ---------------------------------------------------------------------------
// cover[b,l] = sum_n (mask[b,n,l] > 0.5)
// ---------------------------------------------------------------------------
__global__ __launch_bounds__(256) void cover_kernel(const float* __restrict__ mask,
                                                    float* __restrict__ cover) {
  int tid = blockIdx.x * 256 + threadIdx.x;
  int b = tid >> 12, l = tid & 4095;
  float c = 0.f;
#pragma unroll
  for (int n = 0; n < 8; n++)
    c += (mask[(size_t)(b * 8 + n) * 4096 + l] > 0.5f) ? 1.f : 0.f;
  cover[tid] = c;
}

// ---------------------------------------------------------------------------
// Attention v5, IN-PLACE on fp32 QO.
// ---------------------------------------------------------------------------
__global__ __launch_bounds__(256) void attn_kernel(float* QO,                    // (B*4096,1024)
                                                   const bf16* __restrict__ Kp,  // (16,80,1024)
                                                   const bf16* __restrict__ Vt,  // (16,1024,96)
                                                   const float* __restrict__ mask) { // (2,8,4096)
  __shared__ __align__(16) bf16 kl[80 * 72];        // K tile: [t][64 + 8 pad]
  __shared__ __align__(16) bf16 vl[64 * 104];       // V tile: [d][96 + 8 pad]
  __shared__ __align__(16) bf16 p_lds[4][32 * 104]; // per-wave P
  const int tid = threadIdx.x;
  const int lane = tid & 63, wave = tid >> 6;
  const int l16 = lane & 15, quad = lane >> 4;
  const int bid = blockIdx.x;            // 1024 blocks
  const int qg = bid & 31;
  const int h = (bid >> 5) & 15;
  const int b = bid >> 9;
  const int qrow0 = qg * 128 + wave * 32;
  bf16* pl = &p_lds[wave][0];

  // zero PV padding cols 80..95 of own wave's P (softmax writes only 0..79)
  for (int i = lane; i < 32 * 16; i += 64) {
    int r = i >> 4, c = 80 + (i & 15);
    pl[r * 104 + c] = (bf16)0.f;
  }

  // Q fragments (B-operand of S^T = K*Q^T)
  bf16x8 qf[2][2];
#pragma unroll
  for (int mi = 0; mi < 2; mi++)
#pragma unroll
    for (int ks = 0; ks < 2; ks++)
      qf[mi][ks] = cvt8(QO + (size_t)(b * 4096 + qrow0 + mi * 16 + l16) * 1024 +
                        h * 64 + ks * 32 + quad * 8);

  // preload region masks for this lane's q-rows (m = mi*16 + l16), all n
  float rgf[2][8];
#pragma unroll
  for (int mi = 0; mi < 2; mi++)
#pragma unroll
    for (int n = 0; n < 8; n++)
      rgf[mi][n] = (mask[(size_t)(b * 8 + n) * 4096 + qrow0 + mi * 16 + l16] > 0.5f)
                       ? 1.f : 0.f;

  f32x4 oacc[2][4];
#pragma unroll
  for (int mi = 0; mi < 2; mi++)
#pragma unroll
    for (int nt = 0; nt < 4; nt++)
#pragma unroll
      for (int r = 0; r < 4; r++) oacc[mi][nt][r] = 0.f;

  for (int n = 0; n < 8; n++) {
    const int bn = b * 8 + n;
    const bf16* Ksrc = Kp + (size_t)bn * 80 * 1024 + h * 64;      // 80 rows x 128 B
    const bf16* Vsrc = Vt + (size_t)bn * 1024 * 96 + (size_t)h * 64 * 96;  // 64 rows x 192 B

    // --- cooperative staging: K (640 x 16B chunks), V (768 x 16B chunks) ---
    for (int i = tid; i < 640; i += 256) {
      int row = i >> 3, c8 = (i & 7) * 8;
      *(bf16x8*)(kl + row * 72 + c8) = *(const bf16x8*)(Ksrc + (size_t)row * 1024 + c8);
    }
    for (int i = tid; i < 768; i += 256) {
      int row = i / 12, c8 = (i % 12) * 8;
      *(bf16x8*)(vl + row * 104 + c8) = *(const bf16x8*)(Vsrc + (size_t)row * 96 + c8);
    }
    __syncthreads();  // staging visible

    // --- S^T[t][m] = K Q^T from LDS K-tile ---
    f32x4 s[2][5];
#pragma unroll
    for (int mi = 0; mi < 2; mi++)
#pragma unroll
      for (int tt = 0; tt < 5; tt++)
#pragma unroll
        for (int r = 0; r < 4; r++) s[mi][tt][r] = 0.f;

#pragma unroll
    for (int tt = 0; tt < 5; tt++) {
      int t = tt * 16 + l16;
      bf16x8 kf0 = *(const bf16x8*)(kl + t * 72 + quad * 8);
      bf16x8 kf1 = *(const bf16x8*)(kl + t * 72 + 32 + quad * 8);
#pragma unroll
      for (int mi = 0; mi < 2; mi++) {
        s[mi][tt] = MFMA16(kf0, qf[mi][0], s[mi][tt]);
        s[mi][tt] = MFMA16(kf1, qf[mi][1], s[mi][tt]);
      }
    }

    // --- softmax over t; fold (region-mask * 1/sum) into P pack ---
#pragma unroll
    for (int mi = 0; mi < 2; mi++) {
      float sum = 0.f;
#pragma unroll
      for (int tt = 0; tt < 5; tt++) {
#pragma unroll
        for (int r = 0; r < 4; r++) {
          float e = __expf(s[mi][tt][r] * 0.125f);
          if (tt == 4 && quad * 4 + r >= 13) e = 0.f;  // t >= 77 masked
          s[mi][tt][r] = e;
          sum += e;
        }
      }
      sum += __shfl_xor(sum, 16);
      sum += __shfl_xor(sum, 32);
      float scale = rgf[mi][n] / sum;
#pragma unroll
      for (int tt = 0; tt < 5; tt++) {
        bf16x4 w;
#pragma unroll
        for (int r = 0; r < 4; r++) w[r] = (bf16)(s[mi][tt][r] * scale);
        *(bf16x4*)(pl + (mi * 16 + l16) * 104 + tt * 16 + quad * 4) = w;
      }
    }

    // --- oacc += P V  (C-operand accumulation; P pre-masked+normalized) ---
#pragma unroll
    for (int ks = 0; ks < 3; ks++) {
      bf16x8 pf[2];
#pragma unroll
      for (int mi = 0; mi < 2; mi++)
        pf[mi] = *(const bf16x8*)(pl + (mi * 16 + l16) * 104 + ks * 32 + quad * 8);
#pragma unroll
      for (int nt = 0; nt < 4; nt++) {
        bf16x8 vf = *(const bf16x8*)(vl + (nt * 16 + l16) * 104 + ks * 32 + quad * 8);
#pragma unroll
        for (int mi = 0; mi < 2; mi++) oacc[mi][nt] = MFMA16(pf[mi], vf, oacc[mi][nt]);
      }
    }
    __syncthreads();  // all K/V reads done before next staging
  }

  // overwrite this wave's own Q tile with the masked attention sum
#pragma unroll
  for (int mi = 0; mi < 2; mi++)
#pragma unroll
    for (int r = 0; r < 4; r++) {
      size_t row = (size_t)(b * 4096 + qrow0 + mi * 16 + quad * 4 + r);
#pragma unroll
      for (int nt = 0; nt < 4; nt++)
        QO[row * 1024 + h * 64 + nt * 16 + l16] = oacc[mi][nt][r];
    }
}

// ---------------------------------------------------------------------------
// In-place fp32: QO = QO @ WoT^T + cover*bo + (1-cover)*null + x  (8192x1024)
// ---------------------------------------------------------------------------
__global__ __launch_bounds__(512) void gemm_wo_ep(float* QO,
                                                  const bf16* __restrict__ WoT,
                                                  const float* __restrict__ x,
                                                  const float* __restrict__ bo,
                                                  const float* __restrict__ nullf,
                                                  const float* __restrict__ cover) {
  __shared__ __align__(16) bf16 lds_a[32 * 32 * 32];  // [kt][row][kin]
  const int tid = threadIdx.x;
  const int lane = tid & 63, wv = tid >> 6;
  const int l16 = lane & 15, quad = lane >> 4;
  const int m0 = blockIdx.x * 32;

#pragma unroll
  for (int c = 0; c < 16; c++) {
    int ch = c * 512 + tid;
    int row = ch >> 8;
    int pos4 = (ch & 255) * 4;
    int kt = pos4 >> 5, kin = pos4 & 31;
    f32x4 v = *(const f32x4*)(QO + (size_t)(m0 + row) * 1024 + pos4);
    bf16x4 w;
    w[0] = (bf16)v[0]; w[1] = (bf16)v[1]; w[2] = (bf16)v[2]; w[3] = (bf16)v[3];
    *(bf16x4*)(lds_a + kt * 1024 + row * 32 + kin) = w;
  }
  __syncthreads();

  const int n0 = wv * 128;
  f32x4 acc[2][8];
#pragma unroll
  for (int mi = 0; mi < 2; mi++)
#pragma unroll
    for (int ni = 0; ni < 8; ni++)
#pragma unroll
      for (int r = 0; r < 4; r++) acc[mi][ni][r] = 0.f;

  for (int kt = 0; kt < 32; kt++) {
    bf16x8 a[2];
#pragma unroll
    for (int mi = 0; mi < 2; mi++)
      a[mi] = *(const bf16x8*)(lds_a + kt * 1024 + (mi * 16 + l16) * 32 + quad * 8);
    bf16x8 bfr[8];
#pragma unroll
    for (int ni = 0; ni < 8; ni++)
      bfr[ni] = *(const bf16x8*)(WoT + (size_t)(n0 + ni * 16 + l16) * 1024 + kt * 32 + quad * 8);
#pragma unroll
    for (int mi = 0; mi < 2; mi++)
#pragma unroll
      for (int ni = 0; ni < 8; ni++) acc[mi][ni] = MFMA16(a[mi], bfr[ni], acc[mi][ni]);
  }

#pragma unroll
  for (int mi = 0; mi < 2; mi++)
#pragma unroll
    for (int r = 0; r < 4; r++) {
      int row = m0 + mi * 16 + quad * 4 + r;
      float cv = cover[row];
#pragma unroll
      for (int ni = 0; ni < 8; ni++) {
        int col = n0 + ni * 16 + l16;
        float v = acc[mi][ni][r] + cv * bo[col] + (1.f - cv) * nullf[col] +
                  x[(size_t)row * 1024 + col];
        QO[(size_t)row * 1024 + col] = v;
      }
    }
}

// ---------------------------------------------------------------------------
extern "C" void kernel_launch(void* const* d_in, const int* in_sizes, int n_in,
                              void* d_out, int out_size, void* d_ws, size_t ws_size,
                              hipStream_t stream) {
  const float* x     = (const float*)d_in[0];
  const float* masks = (const float*)d_in[1];
  const float* text  = (const float*)d_in[2];
  const float* Wq    = (const float*)d_in[3];
  const float* Wk    = (const float*)d_in[4];
  const float* Wv    = (const float*)d_in[5];
  const float* Wo    = (const float*)d_in[6];
  const float* bo    = (const float*)d_in[7];
  const float* nullf = (const float*)d_in[8];
  float* out = (float*)d_out;

  // workspace: 13,139,968 bytes
  bf16* ws  = (bf16*)d_ws;
  bf16* WqT = ws;                  // 1024*1024
  bf16* WkT = WqT + 1048576;       // 1024*768
  bf16* WvT = WkT + 786432;        // 1024*768
  bf16* WoT = WvT + 786432;        // 1024*1024
  bf16* Kp  = WoT + 1048576;       // 16*80*1024
  bf16* Vt  = Kp + 1310720;        // 16*1024*96
  float* cover = (float*)(Vt + 1572864);  // 8192 f32

  transpose_cvt_k<<<dim3(32, 32), 256, 0, stream>>>(Wq, WqT, 1024, 1024);
  transpose_cvt_k<<<dim3(32, 24), 256, 0, stream>>>(Wk, WkT, 768, 1024);
  transpose_cvt_k<<<dim3(32, 24), 256, 0, stream>>>(Wv, WvT, 768, 1024);
  transpose_cvt_k<<<dim3(32, 32), 256, 0, stream>>>(Wo, WoT, 1024, 1024);

  gemm_q_kernel<<<dim3(4, 128), 256, 0, stream>>>(x, WqT, out);
  gemm_k_pad<<<dim3(8, 16), 256, 0, stream>>>(text, WkT, Kp);
  gemm_v_t<<<dim3(8, 16), 256, 0, stream>>>(text, WvT, Vt);

  cover_kernel<<<32, 256, 0, stream>>>(masks, cover);
  attn_kernel<<<1024, 256, 0, stream>>>(out, Kp, Vt, masks);

  gemm_wo_ep<<<256, 512, 0, stream>>>(out, WoT, x, bo, nullf, cover);
}

// Round 8
// 355.067 us; speedup vs baseline: 1.3355x; 1.1006x over previous
//
#include <hip/hip_runtime.h>

// ---------------------------------------------------------------------------
// RegionalCrossAttention on MI355X (gfx950).  fp32 in / fp32 out.
// B=2, n=8, L=4096, Lt=77, d=1024, ctx=768, H=16 heads x 64.
//
// Fast path (ws_size >= 29.9 MB):
//   Qb  = (bf16) x@Wq      -> stored bf16 in d_out (dead after attn)
//   Kp  [bn][80][1024] bf16 (t padded to 80, zero rows)
//   Vt  [bn][1024][96] bf16 (transposed, t padded to 96, zeros)
//   attn: block=(b,h,128 q-rows), K/V staged to padded LDS per n,
//         S^T=K*Q^T, mask/norm folded into P, PV accumulates in C-operand;
//         writes ACCb bf16 into ws (out-of-place).
//   out = ACCb@WoT^T + cover*bo + (1-cover)*null + x   (128x128-tile GEMM,
//         dbuf LDS A-staging, fp32 -> d_out, no in-place hazard)
// Fallback (small ws): round-7 pipeline (fp32 Q in d_out, in-place attn,
//   stripe-staged in-place gemm_wo_ep).
// ---------------------------------------------------------------------------

typedef __bf16 bf16;
typedef __bf16 bf16x8 __attribute__((ext_vector_type(8)));
typedef __bf16 bf16x4 __attribute__((ext_vector_type(4)));
typedef float  f32x4  __attribute__((ext_vector_type(4)));

#define MFMA16(a, b, c) __builtin_amdgcn_mfma_f32_16x16x32_bf16((a), (b), (c), 0, 0, 0)

// v_mfma_f32_16x16x32_bf16 layouts (HW-verified, learn_hip m89/m120):
//   A: lane holds A[m = lane&15][k = 8*(lane>>4) + j], j=0..7
//   B: lane holds B[k = 8*(lane>>4) + j][n = lane&15]
//   D: lane,reg r holds D[m = 4*(lane>>4) + r][n = lane&15]

__device__ inline bf16x8 cvt8(const float* p) {
  f32x4 a = *(const f32x4*)p;
  f32x4 b = *(const f32x4*)(p + 4);
  bf16x8 r;
  r[0] = (bf16)a[0]; r[1] = (bf16)a[1]; r[2] = (bf16)a[2]; r[3] = (bf16)a[3];
  r[4] = (bf16)b[0]; r[5] = (bf16)b[1]; r[6] = (bf16)b[2]; r[7] = (bf16)b[3];
  return r;
}

// ---------------------------------------------------------------------------
__global__ __launch_bounds__(256) void transpose_cvt_k(const float* __restrict__ in,
                                                       bf16* __restrict__ out,
                                                       int R, int C) {
  __shared__ bf16 tile[32][33];
  int tx = threadIdx.x & 31, ty = threadIdx.x >> 5;
  int bx = blockIdx.x, by = blockIdx.y;
  int c = bx * 32 + tx;
#pragma unroll
  for (int i = 0; i < 32; i += 8) {
    int r = by * 32 + ty + i;
    tile[ty + i][tx] = (bf16)in[(size_t)r * C + c];
  }
  __syncthreads();
#pragma unroll
  for (int i = 0; i < 32; i += 8) {
    out[(size_t)(bx * 32 + ty + i) * R + by * 32 + tx] = tile[tx][ty + i];
  }
}

// ---------------------------------------------------------------------------
// Q GEMM (fast path): Qb_bf16[8192,1024] = x @ WqT^T.  64m x 256n, BK=32,
// A staged in double-buffered LDS, 4 waves (64n each).
// ---------------------------------------------------------------------------
__global__ __launch_bounds__(256) void gemm_q_b(const float* __restrict__ A,
                                                const bf16* __restrict__ BT,
                                                bf16* __restrict__ C) {
  __shared__ __align__(16) bf16 asA[2][64 * 32];
  const int tid = threadIdx.x;
  const int lane = tid & 63, wave = tid >> 6;
  const int l16 = lane & 15, quad = lane >> 4;
  const int m0 = blockIdx.y * 64;
  const int n0 = blockIdx.x * 256 + wave * 64;
  const int srow = tid >> 2, scol = (tid & 3) * 8;
  const float* aptr = A + (size_t)(m0 + srow) * 1024 + scol;

  *(bf16x8*)(&asA[0][srow * 32 + scol]) = cvt8(aptr);

  f32x4 acc[4][4];
#pragma unroll
  for (int i = 0; i < 4; i++)
#pragma unroll
    for (int j = 0; j < 4; j++)
#pragma unroll
      for (int r = 0; r < 4; r++) acc[i][j][r] = 0.f;

  for (int kt = 0; kt < 32; kt++) {
    bf16x8 wnext;
    if (kt + 1 < 32) wnext = cvt8(aptr + (kt + 1) * 32);
    __syncthreads();
    const bf16* ab = &asA[kt & 1][0];
    bf16x8 a[4], b[4];
#pragma unroll
    for (int mi = 0; mi < 4; mi++)
      a[mi] = *(const bf16x8*)(ab + (mi * 16 + l16) * 32 + quad * 8);
#pragma unroll
    for (int ni = 0; ni < 4; ni++)
      b[ni] = *(const bf16x8*)(BT + (size_t)(n0 + ni * 16 + l16) * 1024 + kt * 32 + quad * 8);
#pragma unroll
    for (int mi = 0; mi < 4; mi++)
#pragma unroll
      for (int ni = 0; ni < 4; ni++) acc[mi][ni] = MFMA16(a[mi], b[ni], acc[mi][ni]);
    if (kt + 1 < 32)
      *(bf16x8*)(&asA[(kt + 1) & 1][srow * 32 + scol]) = wnext;
  }

#pragma unroll
  for (int mi = 0; mi < 4; mi++)
#pragma unroll
    for (int r = 0; r < 4; r++) {
      int row = m0 + mi * 16 + quad * 4 + r;
#pragma unroll
      for (int ni = 0; ni < 4; ni++)
        C[(size_t)row * 1024 + n0 + ni * 16 + l16] = (bf16)acc[mi][ni][r];
    }
}

// Q GEMM (fallback): fp32 out
__global__ __launch_bounds__(256) void gemm_q_f(const float* __restrict__ A,
                                                const bf16* __restrict__ BT,
                                                float* __restrict__ C) {
  __shared__ __align__(16) bf16 asA[2][64 * 32];
  const int tid = threadIdx.x;
  const int lane = tid & 63, wave = tid >> 6;
  const int l16 = lane & 15, quad = lane >> 4;
  const int m0 = blockIdx.y * 64;
  const int n0 = blockIdx.x * 256 + wave * 64;
  const int srow = tid >> 2, scol = (tid & 3) * 8;
  const float* aptr = A + (size_t)(m0 + srow) * 1024 + scol;

  *(bf16x8*)(&asA[0][srow * 32 + scol]) = cvt8(aptr);

  f32x4 acc[4][4];
#pragma unroll
  for (int i = 0; i < 4; i++)
#pragma unroll
    for (int j = 0; j < 4; j++)
#pragma unroll
      for (int r = 0; r < 4; r++) acc[i][j][r] = 0.f;

  for (int kt = 0; kt < 32; kt++) {
    bf16x8 wnext;
    if (kt + 1 < 32) wnext = cvt8(aptr + (kt + 1) * 32);
    __syncthreads();
    const bf16* ab = &asA[kt & 1][0];
    bf16x8 a[4], b[4];
#pragma unroll
    for (int mi = 0; mi < 4; mi++)
      a[mi] = *(const bf16x8*)(ab + (mi * 16 + l16) * 32 + quad * 8);
#pragma unroll
    for (int ni = 0; ni < 4; ni++)
      b[ni] = *(const bf16x8*)(BT + (size_t)(n0 + ni * 16 + l16) * 1024 + kt * 32 + quad * 8);
#pragma unroll
    for (int mi = 0; mi < 4; mi++)
#pragma unroll
      for (int ni = 0; ni < 4; ni++) acc[mi][ni] = MFMA16(a[mi], b[ni], acc[mi][ni]);
    if (kt + 1 < 32)
      *(bf16x8*)(&asA[(kt + 1) & 1][srow * 32 + scol]) = wnext;
  }

#pragma unroll
  for (int mi = 0; mi < 4; mi++)
#pragma unroll
    for (int r = 0; r < 4; r++) {
      int row = m0 + mi * 16 + quad * 4 + r;
#pragma unroll
      for (int ni = 0; ni < 4; ni++)
        C[(size_t)row * 1024 + n0 + ni * 16 + l16] = acc[mi][ni][r];
    }
}

// ---------------------------------------------------------------------------
// K GEMM with padded store: Kp[bn][80][1024] bf16; t rows 77..79 zeroed.
// ---------------------------------------------------------------------------
__global__ __launch_bounds__(256) void gemm_k_pad(const float* __restrict__ text,
                                                  const bf16* __restrict__ WkT,
                                                  bf16* __restrict__ Kp) {
  const int tid = threadIdx.x;
  const int lane = tid & 63, wave = tid >> 6;
  const int l16 = lane & 15, quad = lane >> 4;
  const int m0 = (wave >> 1) * 64;
  const int n0 = blockIdx.x * 128 + (wave & 1) * 64;
  const int bn = blockIdx.y;
  const float* A = text + (size_t)bn * 77 * 768;
  bf16* dst = Kp + (size_t)bn * 80 * 1024;

  f32x4 acc[4][4];
#pragma unroll
  for (int i = 0; i < 4; i++)
#pragma unroll
    for (int j = 0; j < 4; j++)
#pragma unroll
      for (int r = 0; r < 4; r++) acc[i][j][r] = 0.f;

  for (int k0 = 0; k0 < 768; k0 += 32) {
    bf16x8 a[4], b[4];
#pragma unroll
    for (int mi = 0; mi < 4; mi++) {
      int row = m0 + mi * 16 + l16;
      if (row >= 77) row = 76;
      a[mi] = cvt8(A + (size_t)row * 768 + k0 + quad * 8);
    }
#pragma unroll
    for (int ni = 0; ni < 4; ni++)
      b[ni] = *(const bf16x8*)(WkT + (size_t)(n0 + ni * 16 + l16) * 768 + k0 + quad * 8);
#pragma unroll
    for (int mi = 0; mi < 4; mi++)
#pragma unroll
      for (int ni = 0; ni < 4; ni++) acc[mi][ni] = MFMA16(a[mi], b[ni], acc[mi][ni]);
  }

#pragma unroll
  for (int mi = 0; mi < 4; mi++)
#pragma unroll
    for (int r = 0; r < 4; r++) {
      int t = m0 + mi * 16 + quad * 4 + r;
      if (t < 77) {
#pragma unroll
        for (int ni = 0; ni < 4; ni++)
          dst[(size_t)t * 1024 + n0 + ni * 16 + l16] = (bf16)acc[mi][ni][r];
      } else if (t < 80) {
#pragma unroll
        for (int ni = 0; ni < 4; ni++)
          dst[(size_t)t * 1024 + n0 + ni * 16 + l16] = (bf16)0.f;
      }
    }
}

// ---------------------------------------------------------------------------
// V GEMM with TRANSPOSED padded store: Vt[bn][1024][96] bf16, t padded to 96.
// ---------------------------------------------------------------------------
__global__ __launch_bounds__(256) void gemm_v_t(const float* __restrict__ text,
                                                const bf16* __restrict__ WvT,
                                                bf16* __restrict__ Vt) {
  const int tid = threadIdx.x;
  const int lane = tid & 63, wave = tid >> 6;
  const int l16 = lane & 15, quad = lane >> 4;
  const int m0 = (wave >> 1) * 64;
  const int n0 = blockIdx.x * 128 + (wave & 1) * 64;
  const int bn = blockIdx.y;
  const float* A = text + (size_t)bn * 77 * 768;
  bf16* dst = Vt + (size_t)bn * 1024 * 96;

  f32x4 acc[4][4];
#pragma unroll
  for (int i = 0; i < 4; i++)
#pragma unroll
    for (int j = 0; j < 4; j++)
#pragma unroll
      for (int r = 0; r < 4; r++) acc[i][j][r] = 0.f;

  for (int k0 = 0; k0 < 768; k0 += 32) {
    bf16x8 a[4], b[4];
#pragma unroll
    for (int mi = 0; mi < 4; mi++) {
      int row = m0 + mi * 16 + l16;
      if (row >= 77) row = 76;
      a[mi] = cvt8(A + (size_t)row * 768 + k0 + quad * 8);
    }
#pragma unroll
    for (int ni = 0; ni < 4; ni++)
      b[ni] = *(const bf16x8*)(WvT + (size_t)(n0 + ni * 16 + l16) * 768 + k0 + quad * 8);
#pragma unroll
    for (int mi = 0; mi < 4; mi++)
#pragma unroll
      for (int ni = 0; ni < 4; ni++) acc[mi][ni] = MFMA16(a[mi], b[ni], acc[mi][ni]);
  }

#pragma unroll
  for (int mi = 0; mi < 4; mi++) {
    int t0 = m0 + mi * 16 + quad * 4;
#pragma unroll
    for (int ni = 0; ni < 4; ni++) {
      int col = n0 + ni * 16 + l16;
      bf16* cbase = dst + (size_t)col * 96;
      if (t0 + 3 < 77) {
        bf16x4 w;
        w[0] = (bf16)acc[mi][ni][0]; w[1] = (bf16)acc[mi][ni][1];
        w[2] = (bf16)acc[mi][ni][2]; w[3] = (bf16)acc[mi][ni][3];
        *(bf16x4*)(cbase + t0) = w;
      } else {
#pragma unroll
        for (int r = 0; r < 4; r++) {
          int t = t0 + r;
          if (t < 77)      cbase[t] = (bf16)acc[mi][ni][r];
          else if (t < 96) cbase[t] = (bf16)0.f;
        }
      }
    }
  }
}

// ---------------------------------------------------------------------------
__global__ __launch_bounds__(256) void cover_kernel(const float* __restrict__ mask,
                                                    float* __restrict__ cover) {
  int tid = blockIdx.x * 256 + threadIdx.x;
  int b = tid >> 12, l = tid & 4095;
  float c = 0.f;
#pragma unroll
  for (int n = 0; n < 8; n++)
    c += (mask[(size_t)(b * 8 + n) * 4096 + l] > 0.5f) ? 1.f : 0.f;
  cover[tid] = c;
}

// ---------------------------------------------------------------------------
// Attention core (shared by fast/fallback via output type).
// ---------------------------------------------------------------------------
template <typename OutT, typename InT>
__device__ __forceinline__ void attn_body(const InT* Qsrc, OutT* Odst,
                                          const bf16* __restrict__ Kp,
                                          const bf16* __restrict__ Vt,
                                          const float* __restrict__ mask) {
  __shared__ __align__(16) bf16 kl[80 * 72];
  __shared__ __align__(16) bf16 vl[64 * 104];
  __shared__ __align__(16) bf16 p_lds[4][32 * 104];
  const int tid = threadIdx.x;
  const int lane = tid & 63, wave = tid >> 6;
  const int l16 = lane & 15, quad = lane >> 4;
  const int bid = blockIdx.x;
  const int qg = bid & 31;
  const int h = (bid >> 5) & 15;
  const int b = bid >> 9;
  const int qrow0 = qg * 128 + wave * 32;
  bf16* pl = &p_lds[wave][0];

  for (int i = lane; i < 32 * 16; i += 64) {
    int r = i >> 4, c = 80 + (i & 15);
    pl[r * 104 + c] = (bf16)0.f;
  }

  bf16x8 qf[2][2];
#pragma unroll
  for (int mi = 0; mi < 2; mi++)
#pragma unroll
    for (int ks = 0; ks < 2; ks++) {
      const InT* qp = Qsrc + (size_t)(b * 4096 + qrow0 + mi * 16 + l16) * 1024 +
                      h * 64 + ks * 32 + quad * 8;
      if constexpr (sizeof(InT) == 4) qf[mi][ks] = cvt8((const float*)qp);
      else                            qf[mi][ks] = *(const bf16x8*)qp;
    }

  float rgf[2][8];
#pragma unroll
  for (int mi = 0; mi < 2; mi++)
#pragma unroll
    for (int n = 0; n < 8; n++)
      rgf[mi][n] = (mask[(size_t)(b * 8 + n) * 4096 + qrow0 + mi * 16 + l16] > 0.5f)
                       ? 1.f : 0.f;

  f32x4 oacc[2][4];
#pragma unroll
  for (int mi = 0; mi < 2; mi++)
#pragma unroll
    for (int nt = 0; nt < 4; nt++)
#pragma unroll
      for (int r = 0; r < 4; r++) oacc[mi][nt][r] = 0.f;

  for (int n = 0; n < 8; n++) {
    const int bn = b * 8 + n;
    const bf16* Ksrc = Kp + (size_t)bn * 80 * 1024 + h * 64;
    const bf16* Vsrc = Vt + (size_t)bn * 1024 * 96 + (size_t)h * 64 * 96;

    for (int i = tid; i < 640; i += 256) {
      int row = i >> 3, c8 = (i & 7) * 8;
      *(bf16x8*)(kl + row * 72 + c8) = *(const bf16x8*)(Ksrc + (size_t)row * 1024 + c8);
    }
    for (int i = tid; i < 768; i += 256) {
      int row = i / 12, c8 = (i % 12) * 8;
      *(bf16x8*)(vl + row * 104 + c8) = *(const bf16x8*)(Vsrc + (size_t)row * 96 + c8);
    }
    __syncthreads();

    f32x4 s[2][5];
#pragma unroll
    for (int mi = 0; mi < 2; mi++)
#pragma unroll
      for (int tt = 0; tt < 5; tt++)
#pragma unroll
        for (int r = 0; r < 4; r++) s[mi][tt][r] = 0.f;

#pragma unroll
    for (int tt = 0; tt < 5; tt++) {
      int t = tt * 16 + l16;
      bf16x8 kf0 = *(const bf16x8*)(kl + t * 72 + quad * 8);
      bf16x8 kf1 = *(const bf16x8*)(kl + t * 72 + 32 + quad * 8);
#pragma unroll
      for (int mi = 0; mi < 2; mi++) {
        s[mi][tt] = MFMA16(kf0, qf[mi][0], s[mi][tt]);
        s[mi][tt] = MFMA16(kf1, qf[mi][1], s[mi][tt]);
      }
    }

#pragma unroll
    for (int mi = 0; mi < 2; mi++) {
      float sum = 0.f;
#pragma unroll
      for (int tt = 0; tt < 5; tt++) {
#pragma unroll
        for (int r = 0; r < 4; r++) {
          float e = __expf(s[mi][tt][r] * 0.125f);
          if (tt == 4 && quad * 4 + r >= 13) e = 0.f;
          s[mi][tt][r] = e;
          sum += e;
        }
      }
      sum += __shfl_xor(sum, 16);
      sum += __shfl_xor(sum, 32);
      float scale = rgf[mi][n] / sum;
#pragma unroll
      for (int tt = 0; tt < 5; tt++) {
        bf16x4 w;
#pragma unroll
        for (int r = 0; r < 4; r++) w[r] = (bf16)(s[mi][tt][r] * scale);
        *(bf16x4*)(pl + (mi * 16 + l16) * 104 + tt * 16 + quad * 4) = w;
      }
    }

#pragma unroll
    for (int ks = 0; ks < 3; ks++) {
      bf16x8 pf[2];
#pragma unroll
      for (int mi = 0; mi < 2; mi++)
        pf[mi] = *(const bf16x8*)(pl + (mi * 16 + l16) * 104 + ks * 32 + quad * 8);
#pragma unroll
      for (int nt = 0; nt < 4; nt++) {
        bf16x8 vf = *(const bf16x8*)(vl + (nt * 16 + l16) * 104 + ks * 32 + quad * 8);
#pragma unroll
        for (int mi = 0; mi < 2; mi++) oacc[mi][nt] = MFMA16(pf[mi], vf, oacc[mi][nt]);
      }
    }
    __syncthreads();
  }

#pragma unroll
  for (int mi = 0; mi < 2; mi++)
#pragma unroll
    for (int r = 0; r < 4; r++) {
      size_t row = (size_t)(b * 4096 + qrow0 + mi * 16 + quad * 4 + r);
#pragma unroll
      for (int nt = 0; nt < 4; nt++)
        Odst[row * 1024 + h * 64 + nt * 16 + l16] = (OutT)oacc[mi][nt][r];
    }
}

// fast: Q bf16 (in d_out), ACC bf16 (in ws)
__global__ __launch_bounds__(256) void attn_b(const bf16* Qb, bf16* ACCb,
                                              const bf16* __restrict__ Kp,
                                              const bf16* __restrict__ Vt,
                                              const float* __restrict__ mask) {
  attn_body<bf16, bf16>(Qb, ACCb, Kp, Vt, mask);
}
// fallback: fp32 in-place on d_out
__global__ __launch_bounds__(256) void attn_f(float* QO,
                                              const bf16* __restrict__ Kp,
                                              const bf16* __restrict__ Vt,
                                              const float* __restrict__ mask) {
  attn_body<float, float>(QO, QO, Kp, Vt, mask);
}

// ---------------------------------------------------------------------------
// Fast-path final GEMM: out_f32[8192,1024] = ACCb @ WoT^T + epilogue.
// 128x128 block tile, 4 waves (64x64), BK=32 double-buffered LDS A-staging.
// ---------------------------------------------------------------------------
__global__ __launch_bounds__(256) void gemm_wo_ep2(const bf16* __restrict__ A,
                                                   const bf16* __restrict__ BT,
                                                   const float* __restrict__ x,
                                                   const float* __restrict__ bo,
                                                   const float* __restrict__ nullf,
                                                   const float* __restrict__ cover,
                                                   float* __restrict__ out) {
  __shared__ __align__(16) bf16 asA[2][128 * 32];
  const int tid = threadIdx.x;
  const int lane = tid & 63, wave = tid >> 6;
  const int l16 = lane & 15, quad = lane >> 4;
  const int mb = blockIdx.y * 128;
  const int m0 = mb + (wave >> 1) * 64;
  const int n0 = blockIdx.x * 128 + (wave & 1) * 64;
  // staging: 512 bf16x8 chunks, 2 per thread
  const int r0 = (tid * 2) >> 2, c0 = ((tid * 2) & 3) * 8;       // chunk 2*tid
  const int r1 = (tid * 2 + 1) >> 2, c1 = ((tid * 2 + 1) & 3) * 8;

  *(bf16x8*)(&asA[0][r0 * 32 + c0]) = *(const bf16x8*)(A + (size_t)(mb + r0) * 1024 + c0);
  *(bf16x8*)(&asA[0][r1 * 32 + c1]) = *(const bf16x8*)(A + (size_t)(mb + r1) * 1024 + c1);

  f32x4 acc[4][4];
#pragma unroll
  for (int i = 0; i < 4; i++)
#pragma unroll
    for (int j = 0; j < 4; j++)
#pragma unroll
      for (int r = 0; r < 4; r++) acc[i][j][r] = 0.f;

  for (int kt = 0; kt < 32; kt++) {
    bf16x8 p0, p1;
    if (kt + 1 < 32) {
      p0 = *(const bf16x8*)(A + (size_t)(mb + r0) * 1024 + (kt + 1) * 32 + c0);
      p1 = *(const bf16x8*)(A + (size_t)(mb + r1) * 1024 + (kt + 1) * 32 + c1);
    }
    __syncthreads();
    const bf16* ab = &asA[kt & 1][0];
    bf16x8 a[4], b[4];
#pragma unroll
    for (int mi = 0; mi < 4; mi++)
      a[mi] = *(const bf16x8*)(ab + ((wave >> 1) * 64 + mi * 16 + l16) * 32 + quad * 8);
#pragma unroll
    for (int ni = 0; ni < 4; ni++)
      b[ni] = *(const bf16x8*)(BT + (size_t)(n0 + ni * 16 + l16) * 1024 + kt * 32 + quad * 8);
#pragma unroll
    for (int mi = 0; mi < 4; mi++)
#pragma unroll
      for (int ni = 0; ni < 4; ni++) acc[mi][ni] = MFMA16(a[mi], b[ni], acc[mi][ni]);
    if (kt + 1 < 32) {
      *(bf16x8*)(&asA[(kt + 1) & 1][r0 * 32 + c0]) = p0;
      *(bf16x8*)(&asA[(kt + 1) & 1][r1 * 32 + c1]) = p1;
    }
  }

#pragma unroll
  for (int mi = 0; mi < 4; mi++)
#pragma unroll
    for (int r = 0; r < 4; r++) {
      int row = m0 + mi * 16 + quad * 4 + r;
      float cv = cover[row];
#pragma unroll
      for (int ni = 0; ni < 4; ni++) {
        int col = n0 + ni * 16 + l16;
        float v = acc[mi][ni][r] + cv * bo[col] + (1.f - cv) * nullf[col] +
                  x[(size_t)row * 1024 + col];
        out[(size_t)row * 1024 + col] = v;
      }
    }
}

// ---------------------------------------------------------------------------
// Fallback in-place final GEMM (round-7 version).
// ---------------------------------------------------------------------------
__global__ __launch_bounds__(512) void gemm_wo_ep(float* QO,
                                                  const bf16* __restrict__ WoT,
                                                  const float* __restrict__ x,
                                                  const float* __restrict__ bo,
                                                  const float* __restrict__ nullf,
                                                  const float* __restrict__ cover) {
  __shared__ __align__(16) bf16 lds_a[32 * 32 * 32];
  const int tid = threadIdx.x;
  const int lane = tid & 63, wv = tid >> 6;
  const int l16 = lane & 15, quad = lane >> 4;
  const int m0 = blockIdx.x * 32;

#pragma unroll
  for (int c = 0; c < 16; c++) {
    int ch = c * 512 + tid;
    int row = ch >> 8;
    int pos4 = (ch & 255) * 4;
    int kt = pos4 >> 5, kin = pos4 & 31;
    f32x4 v = *(const f32x4*)(QO + (size_t)(m0 + row) * 1024 + pos4);
    bf16x4 w;
    w[0] = (bf16)v[0]; w[1] = (bf16)v[1]; w[2] = (bf16)v[2]; w[3] = (bf16)v[3];
    *(bf16x4*)(lds_a + kt * 1024 + row * 32 + kin) = w;
  }
  __syncthreads();

  const int n0 = wv * 128;
  f32x4 acc[2][8];
#pragma unroll
  for (int mi = 0; mi < 2; mi++)
#pragma unroll
    for (int ni = 0; ni < 8; ni++)
#pragma unroll
      for (int r = 0; r < 4; r++) acc[mi][ni][r] = 0.f;

  for (int kt = 0; kt < 32; kt++) {
    bf16x8 a[2];
#pragma unroll
    for (int mi = 0; mi < 2; mi++)
      a[mi] = *(const bf16x8*)(lds_a + kt * 1024 + (mi * 16 + l16) * 32 + quad * 8);
    bf16x8 bfr[8];
#pragma unroll
    for (int ni = 0; ni < 8; ni++)
      bfr[ni] = *(const bf16x8*)(WoT + (size_t)(n0 + ni * 16 + l16) * 1024 + kt * 32 + quad * 8);
#pragma unroll
    for (int mi = 0; mi < 2; mi++)
#pragma unroll
      for (int ni = 0; ni < 8; ni++) acc[mi][ni] = MFMA16(a[mi], bfr[ni], acc[mi][ni]);
  }

#pragma unroll
  for (int mi = 0; mi < 2; mi++)
#pragma unroll
    for (int r = 0; r < 4; r++) {
      int row = m0 + mi * 16 + quad * 4 + r;
      float cv = cover[row];
#pragma unroll
      for (int ni = 0; ni < 8; ni++) {
        int col = n0 + ni * 16 + l16;
        float v = acc[mi][ni][r] + cv * bo[col] + (1.f - cv) * nullf[col] +
                  x[(size_t)row * 1024 + col];
        QO[(size_t)row * 1024 + col] = v;
      }
    }
}

// ---------------------------------------------------------------------------
extern "C" void kernel_launch(void* const* d_in, const int* in_sizes, int n_in,
                              void* d_out, int out_size, void* d_ws, size_t ws_size,
                              hipStream_t stream) {
  const float* x     = (const float*)d_in[0];
  const float* masks = (const float*)d_in[1];
  const float* text  = (const float*)d_in[2];
  const float* Wq    = (const float*)d_in[3];
  const float* Wk    = (const float*)d_in[4];
  const float* Wv    = (const float*)d_in[5];
  const float* Wo    = (const float*)d_in[6];
  const float* bo    = (const float*)d_in[7];
  const float* nullf = (const float*)d_in[8];
  float* out = (float*)d_out;

  bf16* ws  = (bf16*)d_ws;
  bf16* WqT = ws;                  // 1024*1024
  bf16* WkT = WqT + 1048576;       // 1024*768
  bf16* WvT = WkT + 786432;        // 1024*768
  bf16* WoT = WvT + 786432;        // 1024*1024
  bf16* Kp  = WoT + 1048576;       // 16*80*1024
  bf16* Vt  = Kp + 1310720;        // 16*1024*96
  float* cover = (float*)(Vt + 1572864);          // 8192 f32
  bf16* ACCb = (bf16*)(cover + 8192);             // 8192*1024 bf16 (fast path)
  const size_t NEEDED = 13139968 + 16777216;      // 29,917,184 B

  transpose_cvt_k<<<dim3(32, 32), 256, 0, stream>>>(Wq, WqT, 1024, 1024);
  transpose_cvt_k<<<dim3(32, 24), 256, 0, stream>>>(Wk, WkT, 768, 1024);
  transpose_cvt_k<<<dim3(32, 24), 256, 0, stream>>>(Wv, WvT, 768, 1024);
  transpose_cvt_k<<<dim3(32, 32), 256, 0, stream>>>(Wo, WoT, 1024, 1024);

  gemm_k_pad<<<dim3(8, 16), 256, 0, stream>>>(text, WkT, Kp);
  gemm_v_t<<<dim3(8, 16), 256, 0, stream>>>(text, WvT, Vt);
  cover_kernel<<<32, 256, 0, stream>>>(masks, cover);

  if (ws_size >= NEEDED) {
    bf16* Qb = (bf16*)d_out;  // bf16 Q in d_out; dead after attn_b
    gemm_q_b<<<dim3(4, 128), 256, 0, stream>>>(x, WqT, Qb);
    attn_b<<<1024, 256, 0, stream>>>(Qb, ACCb, Kp, Vt, masks);
    gemm_wo_ep2<<<dim3(8, 64), 256, 0, stream>>>(ACCb, WoT, x, bo, nullf, cover, out);
  } else {
    gemm_q_f<<<dim3(4, 128), 256, 0, stream>>>(x, WqT, out);
    attn_f<<<1024, 256, 0, stream>>>(out, Kp, Vt, masks);
    gemm_wo_ep<<<256, 512, 0, stream>>>(out, WoT, x, bo, nullf, cover);
  }
}